// Round 11
// baseline (386.866 us; speedup 1.0000x reference)
//
#include <hip/hip_runtime.h>
#include <cmath>

#define N_NODES 100000
#define N_EDGES 1600000
#define IN_DIM 128
#define HID 96
#define NCLS 16
#define NB_SCAN 391   // ceil(N_NODES/256)
#define NB_GATH 2048  // gather grid (fixed, for stats partials)

// bucket-sort CSR build (contention-free)
#define BSHIFT 7
#define BNODES 128                 // nodes per bucket
#define NBUK 782                   // ceil(N_NODES/128)
#define TILE_E 16384               // edges per tile
#define NBLK_E 98                  // ceil(N_EDGES/TILE_E)
#define NBLK_Q 12                  // NBLK_E/8
#define NBLK_R 2                   // NBLK_E%8

typedef unsigned int uint;
typedef unsigned short ushort;

__device__ __forceinline__ ushort f2bf(float x) {  // RNE f32->bf16
    uint b = __float_as_uint(x);
    uint r = (b + 0x7FFFu + ((b >> 16) & 1u)) >> 16;
    return (ushort)r;
}
__device__ __forceinline__ float bf_lo(uint w) { return __uint_as_float(w << 16); }
__device__ __forceinline__ float bf_hi(uint w) { return __uint_as_float(w & 0xFFFF0000u); }
__device__ __forceinline__ uint pack2bf(float a, float b) {
    return (uint)f2bf(a) | ((uint)f2bf(b) << 16);
}
__device__ __forceinline__ float4 bn_relu4(float4 x, float4 sc, float4 sh) {
    float4 r;
    r.x = fmaxf(fmaf(x.x, sc.x, sh.x), 0.f);
    r.y = fmaxf(fmaf(x.y, sc.y, sh.y), 0.f);
    r.z = fmaxf(fmaf(x.z, sc.z, sh.z), 0.f);
    r.w = fmaxf(fmaf(x.w, sc.w, sh.w), 0.f);
    return r;
}

// XCD-swizzled tile mapping (bijective for NBLK_E = 8*NBLK_Q + NBLK_R).
__device__ __forceinline__ int tile_of(int blk) {
    int xcd = blk & 7, slot = blk >> 3;
    return (xcd < NBLK_R) ? xcd * (NBLK_Q + 1) + slot
                          : NBLK_R * (NBLK_Q + 1) + (xcd - NBLK_R) * NBLK_Q + slot;
}

// ---------------------------------------------------------------------------
// wfuse: Wf[128][96] = W_emb @ W1 ; bf[96] = b_emb @ W1
// ---------------------------------------------------------------------------
__global__ __launch_bounds__(256) void wfuse(const float* __restrict__ W_emb,
                                             const float* __restrict__ W1,
                                             const float* __restrict__ b_emb,
                                             float* __restrict__ Wf,
                                             float* __restrict__ bf) {
    __shared__ float W1s[HID * HID];
    for (int i = threadIdx.x; i < HID * HID / 4; i += 256)
        ((float4*)W1s)[i] = ((const float4*)W1)[i];
    __syncthreads();
    int idx = blockIdx.x * 256 + threadIdx.x;
    if (idx < IN_DIM * HID) {
        int i = idx / HID, j = idx - (idx / HID) * HID;
        float acc = 0.f;
        for (int k = 0; k < HID; ++k)
            acc = fmaf(W_emb[(size_t)i * HID + k], W1s[k * HID + j], acc);
        Wf[idx] = acc;
    }
    if (idx < HID) {
        float acc = 0.f;
        for (int k = 0; k < HID; ++k)
            acc = fmaf(b_emb[k], W1s[k * HID + idx], acc);
        bf[idx] = acc;
    }
}

// ---------------------------------------------------------------------------
// Layer-1 GEMM (f32 input): T1 = X @ Wf + bf -> bf16 table.
// 192 thr = 32 clusters x 6 col-groups; thread = 2 rows x 16 cols.
// K-phased W staging (KP=64): LDS 24.7 KB -> 6 blocks/CU; grid 1563 blocks
// -> ~57% occupancy ceiling (round-10: 49.7 KB + 782 blocks = 11% measured).
// GSTRIDE = KP*16+4 == 4 mod 32 -> 6 groups on distinct bank quads.
// ---------------------------------------------------------------------------
__global__ __launch_bounds__(192) void gemm_l1(const float* __restrict__ X,
                                               const float* __restrict__ W,
                                               const float* __restrict__ bias,
                                               ushort* __restrict__ outB) {
    constexpr int K = IN_DIM, KP = 64;
    constexpr int GSTRIDE = KP * 16 + 4;
    __shared__ float Ws[6 * GSTRIDE];
    __shared__ float bs[HID];
    if (threadIdx.x < HID) bs[threadIdx.x] = bias[threadIdx.x];

    const int g = threadIdx.x % 6;
    const int rc = threadIdx.x / 6;
    const int rbase = blockIdx.x * 64 + rc * 2;
    const int r0 = min(rbase + 0, N_NODES - 1);
    const int r1 = min(rbase + 1, N_NODES - 1);
    const float* x0 = X + (size_t)r0 * K;
    const float* x1 = X + (size_t)r1 * K;
    const float* wg = Ws + g * GSTRIDE;

    float acc[2][16];
#pragma unroll
    for (int j = 0; j < 16; ++j) { acc[0][j] = 0.f; acc[1][j] = 0.f; }

    for (int ph = 0; ph < K / KP; ++ph) {
        if (ph) __syncthreads();  // all readers done with previous phase
        for (int i = threadIdx.x; i < KP * HID / 4; i += 192) {
            int flat = i * 4;
            int k = flat / HID, c = flat - k * HID;
            int gg = c / 16, j = c - gg * 16;
            *(float4*)&Ws[gg * GSTRIDE + k * 16 + j] =
                *(const float4*)(W + (size_t)(ph * KP + k) * HID + c);
        }
        __syncthreads();
        const float* xp0 = x0 + ph * KP;
        const float* xp1 = x1 + ph * KP;
        for (int k = 0; k < KP; k += 4) {
            float4 a0 = *(const float4*)(xp0 + k);
            float4 a1 = *(const float4*)(xp1 + k);
#pragma unroll
            for (int kk = 0; kk < 4; ++kk) {
                const float* wrow = wg + (k + kk) * 16;
                float4 w0 = *(const float4*)(wrow + 0);
                float4 w1 = *(const float4*)(wrow + 4);
                float4 w2 = *(const float4*)(wrow + 8);
                float4 w3 = *(const float4*)(wrow + 12);
                float xs0 = kk == 0 ? a0.x : kk == 1 ? a0.y : kk == 2 ? a0.z : a0.w;
                float xs1 = kk == 0 ? a1.x : kk == 1 ? a1.y : kk == 2 ? a1.z : a1.w;
                const float wv[16] = {w0.x, w0.y, w0.z, w0.w, w1.x, w1.y, w1.z, w1.w,
                                      w2.x, w2.y, w2.z, w2.w, w3.x, w3.y, w3.z, w3.w};
#pragma unroll
                for (int j = 0; j < 16; ++j) {
                    acc[0][j] = fmaf(xs0, wv[j], acc[0][j]);
                    acc[1][j] = fmaf(xs1, wv[j], acc[1][j]);
                }
            }
        }
    }
    const int rr[2] = {r0, r1};
#pragma unroll
    for (int i = 0; i < 2; ++i) {
        const float* bb = &bs[g * 16];
        ushort* orow = outB + (size_t)rr[i] * HID + g * 16;
        uint4 p0, p1;
        p0.x = pack2bf(acc[i][0] + bb[0], acc[i][1] + bb[1]);
        p0.y = pack2bf(acc[i][2] + bb[2], acc[i][3] + bb[3]);
        p0.z = pack2bf(acc[i][4] + bb[4], acc[i][5] + bb[5]);
        p0.w = pack2bf(acc[i][6] + bb[6], acc[i][7] + bb[7]);
        p1.x = pack2bf(acc[i][8] + bb[8], acc[i][9] + bb[9]);
        p1.y = pack2bf(acc[i][10] + bb[10], acc[i][11] + bb[11]);
        p1.z = pack2bf(acc[i][12] + bb[12], acc[i][13] + bb[13]);
        p1.w = pack2bf(acc[i][14] + bb[14], acc[i][15] + bb[15]);
        *(uint4*)(orow + 0) = p0;
        *(uint4*)(orow + 8) = p1;
    }
}

// ---------------------------------------------------------------------------
// Layer-2 GEMM (bf16 input + fused BN1+ReLU): T2 = relu(bn(z1)) @ W2 -> bf16.
// Same 2-row structure, KP=48 (LDS 18.5 KB).
// ---------------------------------------------------------------------------
__global__ __launch_bounds__(192) void gemm_l2(const ushort* __restrict__ X,
                                               const float* __restrict__ W,
                                               const float* __restrict__ scale,
                                               const float* __restrict__ shift,
                                               ushort* __restrict__ outB) {
    constexpr int K = HID, KP = 48;
    constexpr int GSTRIDE = KP * 16 + 4;
    __shared__ float Ws[6 * GSTRIDE];
    __shared__ float scs[HID], shs[HID];
    if (threadIdx.x < HID) {
        scs[threadIdx.x] = scale[threadIdx.x];
        shs[threadIdx.x] = shift[threadIdx.x];
    }

    const int g = threadIdx.x % 6;
    const int rc = threadIdx.x / 6;
    const int rbase = blockIdx.x * 64 + rc * 2;
    const int r0 = min(rbase + 0, N_NODES - 1);
    const int r1 = min(rbase + 1, N_NODES - 1);
    const ushort* x0 = X + (size_t)r0 * K;
    const ushort* x1 = X + (size_t)r1 * K;
    const float* wg = Ws + g * GSTRIDE;

    float acc[2][16];
#pragma unroll
    for (int j = 0; j < 16; ++j) { acc[0][j] = 0.f; acc[1][j] = 0.f; }

    for (int ph = 0; ph < K / KP; ++ph) {
        if (ph) __syncthreads();
        for (int i = threadIdx.x; i < KP * HID / 4; i += 192) {
            int flat = i * 4;
            int k = flat / HID, c = flat - k * HID;
            int gg = c / 16, j = c - gg * 16;
            *(float4*)&Ws[gg * GSTRIDE + k * 16 + j] =
                *(const float4*)(W + (size_t)(ph * KP + k) * HID + c);
        }
        __syncthreads();
        const ushort* xp0 = x0 + ph * KP;
        const ushort* xp1 = x1 + ph * KP;
        for (int k = 0; k < KP; k += 4) {
            uint2 u0 = *(const uint2*)(xp0 + k);
            uint2 u1 = *(const uint2*)(xp1 + k);
            float4 sc4 = *(const float4*)(scs + ph * KP + k);  // uniform broadcast
            float4 sh4 = *(const float4*)(shs + ph * KP + k);
            float4 a0 = bn_relu4(make_float4(bf_lo(u0.x), bf_hi(u0.x), bf_lo(u0.y), bf_hi(u0.y)), sc4, sh4);
            float4 a1 = bn_relu4(make_float4(bf_lo(u1.x), bf_hi(u1.x), bf_lo(u1.y), bf_hi(u1.y)), sc4, sh4);
#pragma unroll
            for (int kk = 0; kk < 4; ++kk) {
                const float* wrow = wg + (k + kk) * 16;
                float4 w0 = *(const float4*)(wrow + 0);
                float4 w1 = *(const float4*)(wrow + 4);
                float4 w2 = *(const float4*)(wrow + 8);
                float4 w3 = *(const float4*)(wrow + 12);
                float xs0 = kk == 0 ? a0.x : kk == 1 ? a0.y : kk == 2 ? a0.z : a0.w;
                float xs1 = kk == 0 ? a1.x : kk == 1 ? a1.y : kk == 2 ? a1.z : a1.w;
                const float wv[16] = {w0.x, w0.y, w0.z, w0.w, w1.x, w1.y, w1.z, w1.w,
                                      w2.x, w2.y, w2.z, w2.w, w3.x, w3.y, w3.z, w3.w};
#pragma unroll
                for (int j = 0; j < 16; ++j) {
                    acc[0][j] = fmaf(xs0, wv[j], acc[0][j]);
                    acc[1][j] = fmaf(xs1, wv[j], acc[1][j]);
                }
            }
        }
    }
    const int rr[2] = {r0, r1};
#pragma unroll
    for (int i = 0; i < 2; ++i) {
        ushort* orow = outB + (size_t)rr[i] * HID + g * 16;
        uint4 p0, p1;
        p0.x = pack2bf(acc[i][0], acc[i][1]);
        p0.y = pack2bf(acc[i][2], acc[i][3]);
        p0.z = pack2bf(acc[i][4], acc[i][5]);
        p0.w = pack2bf(acc[i][6], acc[i][7]);
        p1.x = pack2bf(acc[i][8], acc[i][9]);
        p1.y = pack2bf(acc[i][10], acc[i][11]);
        p1.z = pack2bf(acc[i][12], acc[i][13]);
        p1.w = pack2bf(acc[i][14], acc[i][15]);
        *(uint4*)(orow + 0) = p0;
        *(uint4*)(orow + 8) = p1;
    }
}

// ---------------------------------------------------------------------------
// CSR build, contention-free (unchanged from round 9).
// ---------------------------------------------------------------------------
__global__ __launch_bounds__(256) void bin_hist(const int* __restrict__ dst,
                                                int* __restrict__ bcnt) {
    int tile = tile_of(blockIdx.x);
    int beg = tile * TILE_E, end = min(beg + TILE_E, N_EDGES);
    __shared__ int cnt[NBUK];
    for (int b = threadIdx.x; b < NBUK; b += 256) cnt[b] = 0;
    __syncthreads();
    for (int i = beg + threadIdx.x * 4; i < end; i += 256 * 4) {
        int4 d = *(const int4*)(dst + i);
        atomicAdd(&cnt[d.x >> BSHIFT], 1);
        atomicAdd(&cnt[d.y >> BSHIFT], 1);
        atomicAdd(&cnt[d.z >> BSHIFT], 1);
        atomicAdd(&cnt[d.w >> BSHIFT], 1);
    }
    __syncthreads();
    for (int b = threadIdx.x; b < NBUK; b += 256) bcnt[(size_t)b * NBLK_E + tile] = cnt[b];
}

__global__ __launch_bounds__(128) void bin_scanA(const int* __restrict__ bcnt,
                                                 int* __restrict__ boff,
                                                 int* __restrict__ btot) {
    int bin = blockIdx.x, t = threadIdx.x;
    __shared__ int tmp[128];
    int v = (t < NBLK_E) ? bcnt[(size_t)bin * NBLK_E + t] : 0;
    tmp[t] = v;
    __syncthreads();
    for (int off = 1; off < 128; off <<= 1) {
        int a = (t >= off) ? tmp[t - off] : 0;
        __syncthreads();
        tmp[t] += a;
        __syncthreads();
    }
    if (t < NBLK_E) boff[(size_t)bin * NBLK_E + t] = tmp[t] - v;
    if (t == NBLK_E - 1) btot[bin] = tmp[t];
}

__global__ __launch_bounds__(1024) void bin_scanB(const int* __restrict__ btot,
                                                  int* __restrict__ bbase) {
    int t = threadIdx.x;
    __shared__ int tmp[1024];
    int v = (t < NBUK) ? btot[t] : 0;
    tmp[t] = v;
    __syncthreads();
    for (int off = 1; off < 1024; off <<= 1) {
        int a = (t >= off) ? tmp[t - off] : 0;
        __syncthreads();
        tmp[t] += a;
        __syncthreads();
    }
    if (t < NBUK) bbase[t] = tmp[t] - v;
    if (t == 0) bbase[NBUK] = N_EDGES;
}

__global__ __launch_bounds__(256) void bin_scatter(const int* __restrict__ src,
                                                   const int* __restrict__ dst,
                                                   const int* __restrict__ bbase,
                                                   const int* __restrict__ boff,
                                                   int* __restrict__ ebuf) {
    int tile = tile_of(blockIdx.x);
    int beg = tile * TILE_E, end = min(beg + TILE_E, N_EDGES);
    __shared__ int curs[NBUK];
    for (int b = threadIdx.x; b < NBUK; b += 256)
        curs[b] = bbase[b] + boff[(size_t)b * NBLK_E + tile];
    __syncthreads();
    for (int i = beg + threadIdx.x * 4; i < end; i += 256 * 4) {
        int4 d = *(const int4*)(dst + i);
        int4 s = *(const int4*)(src + i);
#pragma unroll
        for (int e = 0; e < 4; ++e) {
            int dv = e == 0 ? d.x : e == 1 ? d.y : e == 2 ? d.z : d.w;
            int sv = e == 0 ? s.x : e == 1 ? s.y : e == 2 ? s.z : s.w;
            int p = atomicAdd(&curs[dv >> BSHIFT], 1);  // LDS atomic: cheap
            ebuf[p] = (sv << BSHIFT) | (dv & (BNODES - 1));
        }
    }
}

__global__ __launch_bounds__(256) void bucket_hist(const int* __restrict__ ebuf,
                                                   const int* __restrict__ bbase,
                                                   int* __restrict__ deg) {
    int b = blockIdx.x;
    int lo = b << BSHIFT;
    __shared__ int cnt[BNODES];
    if (threadIdx.x < BNODES) cnt[threadIdx.x] = 0;
    __syncthreads();
    int beg = bbase[b], end = bbase[b + 1];
    for (int i = beg + threadIdx.x; i < end; i += 256)
        atomicAdd(&cnt[ebuf[i] & (BNODES - 1)], 1);
    __syncthreads();
    if (threadIdx.x < BNODES && lo + threadIdx.x < N_NODES)
        deg[lo + threadIdx.x] = cnt[threadIdx.x];
}

__global__ __launch_bounds__(256) void bucket_place(const int* __restrict__ ebuf,
                                                    const int* __restrict__ bbase,
                                                    const int* __restrict__ rp,
                                                    int* __restrict__ cols) {
    int b = blockIdx.x;
    int lo = b << BSHIFT;
    __shared__ int cur[BNODES];
    if (threadIdx.x < BNODES)
        cur[threadIdx.x] = (lo + threadIdx.x < N_NODES) ? rp[lo + threadIdx.x] : 0;
    __syncthreads();
    int beg = bbase[b], end = bbase[b + 1];
    for (int i = beg + threadIdx.x; i < end; i += 256) {
        int v = ebuf[i];
        int p = atomicAdd(&cur[v & (BNODES - 1)], 1);
        cols[p] = v >> BSHIFT;
    }
}

// ---------------------------------------------------------------------------
// Scan (2-level) over deg -> rp
// ---------------------------------------------------------------------------
__global__ void scan_blocksum(const int* __restrict__ deg, int* __restrict__ bsums) {
    __shared__ int sm[256];
    int t = threadIdx.x;
    int i = blockIdx.x * 256 + t;
    sm[t] = (i < N_NODES) ? deg[i] : 0;
    __syncthreads();
    for (int s = 128; s > 0; s >>= 1) {
        if (t < s) sm[t] += sm[t + s];
        __syncthreads();
    }
    if (t == 0) bsums[blockIdx.x] = sm[0];
}

__global__ void scan_offsets(const int* __restrict__ bsums, int* __restrict__ boffs) {
    __shared__ int tmp[512];
    int t = threadIdx.x;
    int v = (t < NB_SCAN) ? bsums[t] : 0;
    tmp[t] = v;
    __syncthreads();
    for (int off = 1; off < 512; off <<= 1) {
        int a = (t >= off) ? tmp[t - off] : 0;
        __syncthreads();
        tmp[t] += a;
        __syncthreads();
    }
    if (t < NB_SCAN) boffs[t] = tmp[t] - v;  // exclusive
}

__global__ void scan_final(const int* __restrict__ deg, const int* __restrict__ boffs,
                           int* __restrict__ rp) {
    __shared__ int tmp[256];
    int t = threadIdx.x;
    int i = blockIdx.x * 256 + t;
    int val = (i < N_NODES) ? deg[i] : 0;
    tmp[t] = val;
    __syncthreads();
    for (int off = 1; off < 256; off <<= 1) {
        int a = (t >= off) ? tmp[t - off] : 0;
        __syncthreads();
        tmp[t] += a;
        __syncthreads();
    }
    int excl = tmp[t] - val + boffs[blockIdx.x];
    if (i < N_NODES) {
        rp[i] = excl;
        if (i == N_NODES - 1) rp[N_NODES] = excl + val;
    }
}

// ---------------------------------------------------------------------------
// Gather + fused BN stats, 12 lanes/node x 16 B (uint4 = 8 bf16):
// z[v] = bias + T[v] + sum_u T[u], z stored bf16; stats f32 in registers,
// LDS reduce, deterministic per-block partials.
// ---------------------------------------------------------------------------
#define GLANES 12
#define GNODES 16  // 192 threads / 12 lanes

__global__ __launch_bounds__(192) void gather_stats(const ushort* __restrict__ T,
                                                    const int* __restrict__ rp,
                                                    const int* __restrict__ cols,
                                                    const float* __restrict__ bias,
                                                    ushort* __restrict__ z,
                                                    float* __restrict__ psums,
                                                    float* __restrict__ psq) {
    const int q = threadIdx.x % GLANES;   // 8-column chunk
    const int rs = threadIdx.x / GLANES;  // node slot 0..15
    float bia[8];
    {
        float4 b0 = ((const float4*)bias)[q * 2];
        float4 b1 = ((const float4*)bias)[q * 2 + 1];
        bia[0] = b0.x; bia[1] = b0.y; bia[2] = b0.z; bia[3] = b0.w;
        bia[4] = b1.x; bia[5] = b1.y; bia[6] = b1.z; bia[7] = b1.w;
    }
    float s[8], sq[8];
#pragma unroll
    for (int e = 0; e < 8; ++e) { s[e] = 0.f; sq[e] = 0.f; }

#define ADDROW(u)                                                              \
    {                                                                          \
        uint4 w = *(const uint4*)(T + (size_t)(u) * HID + q * 8);              \
        a[0] += bf_lo(w.x); a[1] += bf_hi(w.x);                                \
        a[2] += bf_lo(w.y); a[3] += bf_hi(w.y);                                \
        a[4] += bf_lo(w.z); a[5] += bf_hi(w.z);                                \
        a[6] += bf_lo(w.w); a[7] += bf_hi(w.w);                                \
    }

    for (int v = blockIdx.x * GNODES + rs; v < N_NODES; v += NB_GATH * GNODES) {
        float a[8];
#pragma unroll
        for (int e = 0; e < 8; ++e) a[e] = bia[e];
        ADDROW(v);
        int beg = rp[v], end = rp[v + 1];
        int j = beg;
        for (; j + 3 < end; j += 4) {
            int u0 = cols[j], u1 = cols[j + 1], u2 = cols[j + 2], u3 = cols[j + 3];
            ADDROW(u0); ADDROW(u1); ADDROW(u2); ADDROW(u3);
        }
        for (; j < end; ++j) ADDROW(cols[j]);

        uint4 o;
        o.x = pack2bf(a[0], a[1]);
        o.y = pack2bf(a[2], a[3]);
        o.z = pack2bf(a[4], a[5]);
        o.w = pack2bf(a[6], a[7]);
        *(uint4*)(z + (size_t)v * HID + q * 8) = o;
#pragma unroll
        for (int e = 0; e < 8; ++e) {
            s[e] += a[e];
            sq[e] = fmaf(a[e], a[e], sq[e]);
        }
    }
#undef ADDROW

    __shared__ float red_s[GNODES][GLANES][8];
    __shared__ float red_q[GNODES][GLANES][8];
#pragma unroll
    for (int e = 0; e < 8; ++e) {
        red_s[rs][q][e] = s[e];
        red_q[rs][q][e] = sq[e];
    }
    __syncthreads();
    if (threadIdx.x < HID) {
        int qq = threadIdx.x >> 3, ee = threadIdx.x & 7;
        float S = 0.f, Q = 0.f;
#pragma unroll
        for (int i = 0; i < GNODES; ++i) {
            S += red_s[i][qq][ee];
            Q += red_q[i][qq][ee];
        }
        psums[(size_t)blockIdx.x * HID + threadIdx.x] = S;
        psq[(size_t)blockIdx.x * HID + threadIdx.x] = Q;
    }
}

// ---------------------------------------------------------------------------
__global__ __launch_bounds__(384) void bn_finalize(const float* __restrict__ psums,
                                                   const float* __restrict__ psq,
                                                   const float* __restrict__ g,
                                                   const float* __restrict__ be,
                                                   float* __restrict__ scale,
                                                   float* __restrict__ shift) {
    int c = threadIdx.x % 96, h = threadIdx.x / 96;
    float S = 0.f, Q = 0.f;
    for (int b = h * (NB_GATH / 4); b < (h + 1) * (NB_GATH / 4); ++b) {
        S += psums[(size_t)b * HID + c];
        Q += psq[(size_t)b * HID + c];
    }
    __shared__ float lS[4][96], lQ[4][96];
    lS[h][c] = S;
    lQ[h][c] = Q;
    __syncthreads();
    if (threadIdx.x < 96) {
        S = lS[0][c] + lS[1][c] + lS[2][c] + lS[3][c];
        Q = lQ[0][c] + lQ[1][c] + lQ[2][c] + lQ[3][c];
        float mu = S * (1.0f / N_NODES);
        float var = Q * (1.0f / N_NODES) - mu * mu;
        float rstd = rsqrtf(var + 1e-5f);
        float sc = g[c] * rstd;
        scale[c] = sc;
        shift[c] = be[c] - mu * sc;
    }
}

// ---------------------------------------------------------------------------
// Readout: bf16 input, BN2+ReLU fused during LDS staging, 16 lanes/row
// shuffle log_softmax, coalesced store.
// ---------------------------------------------------------------------------
__global__ __launch_bounds__(256) void readout_kernel(const ushort* __restrict__ X,
                                                      const float* __restrict__ scale,
                                                      const float* __restrict__ shift,
                                                      const float* __restrict__ Wr,
                                                      const float* __restrict__ br,
                                                      float* __restrict__ out) {
    __shared__ float Ws[HID * NCLS];
    __shared__ float XL[16 * 97];
    __shared__ float scs[HID], shs[HID], bs[NCLS];
    for (int i = threadIdx.x; i < HID * NCLS / 4; i += 256)
        ((float4*)Ws)[i] = ((const float4*)Wr)[i];
    if (threadIdx.x < HID) {
        scs[threadIdx.x] = scale[threadIdx.x];
        shs[threadIdx.x] = shift[threadIdx.x];
    }
    if (threadIdx.x < NCLS) bs[threadIdx.x] = br[threadIdx.x];

    int rr = threadIdx.x >> 4, t = threadIdx.x & 15;
    for (int tile = blockIdx.x; tile < N_NODES / 16; tile += gridDim.x) {
        int rbase = tile * 16;
        __syncthreads();
        if (threadIdx.x < 192) {  // 16 rows x 96 cols / 8 per thread
            int base = threadIdx.x * 8;
            int row = base / HID, col = base - (base / HID) * HID;
            uint4 w = *(const uint4*)(X + (size_t)rbase * HID + base);
            float v[8] = {bf_lo(w.x), bf_hi(w.x), bf_lo(w.y), bf_hi(w.y),
                          bf_lo(w.z), bf_hi(w.z), bf_lo(w.w), bf_hi(w.w)};
#pragma unroll
            for (int e = 0; e < 8; ++e)
                XL[row * 97 + col + e] = fmaxf(fmaf(v[e], scs[col + e], shs[col + e]), 0.f);
        }
        __syncthreads();
        float acc = bs[t];
        const float* xrow = &XL[rr * 97];
#pragma unroll 4
        for (int k = 0; k < HID; ++k) acc = fmaf(xrow[k], Ws[k * NCLS + t], acc);
        float m = acc;
#pragma unroll
        for (int off = 8; off; off >>= 1) m = fmaxf(m, __shfl_xor(m, off, 16));
        float e = expf(acc - m);
        float sum = e;
#pragma unroll
        for (int off = 8; off; off >>= 1) sum += __shfl_xor(sum, off, 16);
        float lse = m + logf(sum);
        out[(size_t)rbase * NCLS + threadIdx.x] = acc - lse;
    }
}

// ---------------------------------------------------------------------------
extern "C" void kernel_launch(void* const* d_in, const int* in_sizes, int n_in,
                              void* d_out, int out_size, void* d_ws, size_t ws_size,
                              hipStream_t stream) {
    const float* h     = (const float*)d_in[0];
    const int*   src   = (const int*)d_in[1];
    const int*   dst   = (const int*)d_in[2];
    const float* W_emb = (const float*)d_in[3];
    const float* b_emb = (const float*)d_in[4];
    const float* W1    = (const float*)d_in[5];
    const float* b1    = (const float*)d_in[6];
    const float* g1    = (const float*)d_in[7];
    const float* be1   = (const float*)d_in[8];
    const float* W2    = (const float*)d_in[9];
    const float* b2    = (const float*)d_in[10];
    const float* g2    = (const float*)d_in[11];
    const float* be2   = (const float*)d_in[12];
    const float* Wr    = (const float*)d_in[13];
    const float* br    = (const float*)d_in[14];

    const size_t nh = (size_t)N_NODES * HID;
    ushort* z    = (ushort*)d_ws;             // 19.2 MB bf16 (z1, then z2)
    ushort* T    = z + nh;                    // 19.2 MB bf16 table
    int* deg     = (int*)(T + nh);            // N
    int* rp      = deg + N_NODES;             // N+1
    int* cols    = rp + N_NODES + 1;          // E (6.4 MB)
    int* ebuf    = cols + N_EDGES;            // E (6.4 MB, bucket-sorted packed)
    int* bcnt    = ebuf + N_EDGES;            // NBUK*NBLK_E
    int* boff    = bcnt + NBUK * NBLK_E;      // NBUK*NBLK_E
    int* btot    = boff + NBUK * NBLK_E;      // NBUK
    int* bbase   = btot + NBUK;               // NBUK+1
    int* bsums   = bbase + NBUK + 1;          // 512
    int* boffs   = bsums + 512;               // 512
    float* psums = (float*)(boffs + 512);     // NB_GATH*96
    float* psq   = psums + (size_t)NB_GATH * HID;
    float* scale = psq + (size_t)NB_GATH * HID;   // 96
    float* shift = scale + HID;                    // 96
    float* Wf    = shift + HID;                    // 128*96
    float* bf    = Wf + IN_DIM * HID;              // 96

    const int blkT = (N_NODES + 63) / 64;     // 1563

    // --- CSR build: tile-hist -> scans -> deterministic scatter -> place ---
    bin_hist<<<NBLK_E, 256, 0, stream>>>(dst, bcnt);
    bin_scanA<<<NBUK, 128, 0, stream>>>(bcnt, boff, btot);
    bin_scanB<<<1, 1024, 0, stream>>>(btot, bbase);
    bin_scatter<<<NBLK_E, 256, 0, stream>>>(src, dst, bbase, boff, ebuf);
    bucket_hist<<<NBUK, 256, 0, stream>>>(ebuf, bbase, deg);
    scan_blocksum<<<NB_SCAN, 256, 0, stream>>>(deg, bsums);
    scan_offsets<<<1, 512, 0, stream>>>(bsums, boffs);
    scan_final<<<NB_SCAN, 256, 0, stream>>>(deg, boffs, rp);
    bucket_place<<<NBUK, 256, 0, stream>>>(ebuf, bbase, rp, cols);
    wfuse<<<(IN_DIM * HID + 255) / 256, 256, 0, stream>>>(W_emb, W1, b_emb, Wf, bf);

    // --- layer 1: T1 = h @ Wf + bf (bf16);  z1 = gather(T1) + b1 (+stats) ---
    gemm_l1<<<blkT, 192, 0, stream>>>(h, Wf, bf, T);
    gather_stats<<<NB_GATH, 192, 0, stream>>>(T, rp, cols, b1, z, psums, psq);
    bn_finalize<<<1, 384, 0, stream>>>(psums, psq, g1, be1, scale, shift);

    // --- layer 2: T2 = relu(bn1(z1)) @ W2 (bf16);  z2 = gather(T2) + b2 ---
    gemm_l2<<<blkT, 192, 0, stream>>>(z, W2, scale, shift, T);
    gather_stats<<<NB_GATH, 192, 0, stream>>>(T, rp, cols, b2, z, psums, psq);
    bn_finalize<<<1, 384, 0, stream>>>(psums, psq, g2, be2, scale, shift);

    // --- readout (BN2+ReLU fused) + log_softmax ---
    readout_kernel<<<2048, 256, 0, stream>>>(z, scale, shift, Wr, br, (float*)d_out);
}

// Round 12
// 378.413 us; speedup vs baseline: 1.0223x; 1.0223x over previous
//
#include <hip/hip_runtime.h>
#include <cmath>

#define N_NODES 100000
#define N_EDGES 1600000
#define IN_DIM 128
#define HID 96
#define NCLS 16
#define NB_GATH 2048  // gather grid (fixed, for stats partials)

// bucket-sort CSR build (contention-free)
#define BSHIFT 7
#define BNODES 128                 // nodes per bucket
#define NBUK 782                   // ceil(N_NODES/128)
#define TILE_E 8192                // edges per tile
#define NBLK_E 196                 // ceil(N_EDGES/TILE_E)
#define NBLK_Q 24                  // NBLK_E/8
#define NBLK_R 4                   // NBLK_E%8

typedef unsigned int uint;
typedef unsigned short ushort;

__device__ __forceinline__ ushort f2bf(float x) {  // RNE f32->bf16
    uint b = __float_as_uint(x);
    uint r = (b + 0x7FFFu + ((b >> 16) & 1u)) >> 16;
    return (ushort)r;
}
__device__ __forceinline__ float bf2f(ushort u) {
    return __uint_as_float(((uint)u) << 16);
}
__device__ __forceinline__ float bf_lo(uint w) { return __uint_as_float(w << 16); }
__device__ __forceinline__ float bf_hi(uint w) { return __uint_as_float(w & 0xFFFF0000u); }
__device__ __forceinline__ uint pack2bf(float a, float b) {
    return (uint)f2bf(a) | ((uint)f2bf(b) << 16);
}
__device__ __forceinline__ float4 bn_relu4(float4 x, float4 sc, float4 sh) {
    float4 r;
    r.x = fmaxf(fmaf(x.x, sc.x, sh.x), 0.f);
    r.y = fmaxf(fmaf(x.y, sc.y, sh.y), 0.f);
    r.z = fmaxf(fmaf(x.z, sc.z, sh.z), 0.f);
    r.w = fmaxf(fmaf(x.w, sc.w, sh.w), 0.f);
    return r;
}

// XCD-swizzled tile mapping (bijective for NBLK_E = 8*NBLK_Q + NBLK_R).
__device__ __forceinline__ int tile_of(int blk) {
    int xcd = blk & 7, slot = blk >> 3;
    return (xcd < NBLK_R) ? xcd * (NBLK_Q + 1) + slot
                          : NBLK_R * (NBLK_Q + 1) + (xcd - NBLK_R) * NBLK_Q + slot;
}

// ---------------------------------------------------------------------------
// wfuse: Wf[128][96] = W_emb @ W1 ; bf[96] = b_emb @ W1
// ---------------------------------------------------------------------------
__global__ __launch_bounds__(256) void wfuse(const float* __restrict__ W_emb,
                                             const float* __restrict__ W1,
                                             const float* __restrict__ b_emb,
                                             float* __restrict__ Wf,
                                             float* __restrict__ bf) {
    __shared__ float W1s[HID * HID];
    for (int i = threadIdx.x; i < HID * HID / 4; i += 256)
        ((float4*)W1s)[i] = ((const float4*)W1)[i];
    __syncthreads();
    int idx = blockIdx.x * 256 + threadIdx.x;
    if (idx < IN_DIM * HID) {
        int i = idx / HID, j = idx - (idx / HID) * HID;
        float acc = 0.f;
        for (int k = 0; k < HID; ++k)
            acc = fmaf(W_emb[(size_t)i * HID + k], W1s[k * HID + j], acc);
        Wf[idx] = acc;
    }
    if (idx < HID) {
        float acc = 0.f;
        for (int k = 0; k < HID; ++k)
            acc = fmaf(b_emb[k], W1s[k * HID + idx], acc);
        bf[idx] = acc;
    }
}

// ---------------------------------------------------------------------------
// Layer-1 GEMM (f32 input): T1 = X @ Wf + bf -> bf16 table.
// 192 thr = 32 clusters x 6 col-groups; thread = 2 rows x 16 cols.
// K-phased W staging (KP=64): LDS 24.7 KB. GSTRIDE%32==4 -> conflict-free.
// ---------------------------------------------------------------------------
__global__ __launch_bounds__(192) void gemm_l1(const float* __restrict__ X,
                                               const float* __restrict__ W,
                                               const float* __restrict__ bias,
                                               ushort* __restrict__ outB) {
    constexpr int K = IN_DIM, KP = 64;
    constexpr int GSTRIDE = KP * 16 + 4;
    __shared__ float Ws[6 * GSTRIDE];
    __shared__ float bs[HID];
    if (threadIdx.x < HID) bs[threadIdx.x] = bias[threadIdx.x];

    const int g = threadIdx.x % 6;
    const int rc = threadIdx.x / 6;
    const int rbase = blockIdx.x * 64 + rc * 2;
    const int r0 = min(rbase + 0, N_NODES - 1);
    const int r1 = min(rbase + 1, N_NODES - 1);
    const float* x0 = X + (size_t)r0 * K;
    const float* x1 = X + (size_t)r1 * K;
    const float* wg = Ws + g * GSTRIDE;

    float acc[2][16];
#pragma unroll
    for (int j = 0; j < 16; ++j) { acc[0][j] = 0.f; acc[1][j] = 0.f; }

    for (int ph = 0; ph < K / KP; ++ph) {
        if (ph) __syncthreads();
        for (int i = threadIdx.x; i < KP * HID / 4; i += 192) {
            int flat = i * 4;
            int k = flat / HID, c = flat - k * HID;
            int gg = c / 16, j = c - gg * 16;
            *(float4*)&Ws[gg * GSTRIDE + k * 16 + j] =
                *(const float4*)(W + (size_t)(ph * KP + k) * HID + c);
        }
        __syncthreads();
        const float* xp0 = x0 + ph * KP;
        const float* xp1 = x1 + ph * KP;
        for (int k = 0; k < KP; k += 4) {
            float4 a0 = *(const float4*)(xp0 + k);
            float4 a1 = *(const float4*)(xp1 + k);
#pragma unroll
            for (int kk = 0; kk < 4; ++kk) {
                const float* wrow = wg + (k + kk) * 16;
                float4 w0 = *(const float4*)(wrow + 0);
                float4 w1 = *(const float4*)(wrow + 4);
                float4 w2 = *(const float4*)(wrow + 8);
                float4 w3 = *(const float4*)(wrow + 12);
                float xs0 = kk == 0 ? a0.x : kk == 1 ? a0.y : kk == 2 ? a0.z : a0.w;
                float xs1 = kk == 0 ? a1.x : kk == 1 ? a1.y : kk == 2 ? a1.z : a1.w;
                const float wv[16] = {w0.x, w0.y, w0.z, w0.w, w1.x, w1.y, w1.z, w1.w,
                                      w2.x, w2.y, w2.z, w2.w, w3.x, w3.y, w3.z, w3.w};
#pragma unroll
                for (int j = 0; j < 16; ++j) {
                    acc[0][j] = fmaf(xs0, wv[j], acc[0][j]);
                    acc[1][j] = fmaf(xs1, wv[j], acc[1][j]);
                }
            }
        }
    }
    const int rr[2] = {r0, r1};
#pragma unroll
    for (int i = 0; i < 2; ++i) {
        const float* bb = &bs[g * 16];
        ushort* orow = outB + (size_t)rr[i] * HID + g * 16;
        uint4 p0, p1;
        p0.x = pack2bf(acc[i][0] + bb[0], acc[i][1] + bb[1]);
        p0.y = pack2bf(acc[i][2] + bb[2], acc[i][3] + bb[3]);
        p0.z = pack2bf(acc[i][4] + bb[4], acc[i][5] + bb[5]);
        p0.w = pack2bf(acc[i][6] + bb[6], acc[i][7] + bb[7]);
        p1.x = pack2bf(acc[i][8] + bb[8], acc[i][9] + bb[9]);
        p1.y = pack2bf(acc[i][10] + bb[10], acc[i][11] + bb[11]);
        p1.z = pack2bf(acc[i][12] + bb[12], acc[i][13] + bb[13]);
        p1.w = pack2bf(acc[i][14] + bb[14], acc[i][15] + bb[15]);
        *(uint4*)(orow + 0) = p0;
        *(uint4*)(orow + 8) = p1;
    }
}

// ---------------------------------------------------------------------------
// Layer-2 GEMM (bf16 input + fused BN1+ReLU): T2 = relu(bn(z1)) @ W2 -> bf16.
// Same 2-row structure, KP=48 (LDS 18.5 KB).
// ---------------------------------------------------------------------------
__global__ __launch_bounds__(192) void gemm_l2(const ushort* __restrict__ X,
                                               const float* __restrict__ W,
                                               const float* __restrict__ scale,
                                               const float* __restrict__ shift,
                                               ushort* __restrict__ outB) {
    constexpr int K = HID, KP = 48;
    constexpr int GSTRIDE = KP * 16 + 4;
    __shared__ float Ws[6 * GSTRIDE];
    __shared__ float scs[HID], shs[HID];
    if (threadIdx.x < HID) {
        scs[threadIdx.x] = scale[threadIdx.x];
        shs[threadIdx.x] = shift[threadIdx.x];
    }

    const int g = threadIdx.x % 6;
    const int rc = threadIdx.x / 6;
    const int rbase = blockIdx.x * 64 + rc * 2;
    const int r0 = min(rbase + 0, N_NODES - 1);
    const int r1 = min(rbase + 1, N_NODES - 1);
    const ushort* x0 = X + (size_t)r0 * K;
    const ushort* x1 = X + (size_t)r1 * K;
    const float* wg = Ws + g * GSTRIDE;

    float acc[2][16];
#pragma unroll
    for (int j = 0; j < 16; ++j) { acc[0][j] = 0.f; acc[1][j] = 0.f; }

    for (int ph = 0; ph < K / KP; ++ph) {
        if (ph) __syncthreads();
        for (int i = threadIdx.x; i < KP * HID / 4; i += 192) {
            int flat = i * 4;
            int k = flat / HID, c = flat - k * HID;
            int gg = c / 16, j = c - gg * 16;
            *(float4*)&Ws[gg * GSTRIDE + k * 16 + j] =
                *(const float4*)(W + (size_t)(ph * KP + k) * HID + c);
        }
        __syncthreads();
        const ushort* xp0 = x0 + ph * KP;
        const ushort* xp1 = x1 + ph * KP;
        for (int k = 0; k < KP; k += 4) {
            uint2 u0 = *(const uint2*)(xp0 + k);
            uint2 u1 = *(const uint2*)(xp1 + k);
            float4 sc4 = *(const float4*)(scs + ph * KP + k);  // uniform broadcast
            float4 sh4 = *(const float4*)(shs + ph * KP + k);
            float4 a0 = bn_relu4(make_float4(bf_lo(u0.x), bf_hi(u0.x), bf_lo(u0.y), bf_hi(u0.y)), sc4, sh4);
            float4 a1 = bn_relu4(make_float4(bf_lo(u1.x), bf_hi(u1.x), bf_lo(u1.y), bf_hi(u1.y)), sc4, sh4);
#pragma unroll
            for (int kk = 0; kk < 4; ++kk) {
                const float* wrow = wg + (k + kk) * 16;
                float4 w0 = *(const float4*)(wrow + 0);
                float4 w1 = *(const float4*)(wrow + 4);
                float4 w2 = *(const float4*)(wrow + 8);
                float4 w3 = *(const float4*)(wrow + 12);
                float xs0 = kk == 0 ? a0.x : kk == 1 ? a0.y : kk == 2 ? a0.z : a0.w;
                float xs1 = kk == 0 ? a1.x : kk == 1 ? a1.y : kk == 2 ? a1.z : a1.w;
                const float wv[16] = {w0.x, w0.y, w0.z, w0.w, w1.x, w1.y, w1.z, w1.w,
                                      w2.x, w2.y, w2.z, w2.w, w3.x, w3.y, w3.z, w3.w};
#pragma unroll
                for (int j = 0; j < 16; ++j) {
                    acc[0][j] = fmaf(xs0, wv[j], acc[0][j]);
                    acc[1][j] = fmaf(xs1, wv[j], acc[1][j]);
                }
            }
        }
    }
    const int rr[2] = {r0, r1};
#pragma unroll
    for (int i = 0; i < 2; ++i) {
        ushort* orow = outB + (size_t)rr[i] * HID + g * 16;
        uint4 p0, p1;
        p0.x = pack2bf(acc[i][0], acc[i][1]);
        p0.y = pack2bf(acc[i][2], acc[i][3]);
        p0.z = pack2bf(acc[i][4], acc[i][5]);
        p0.w = pack2bf(acc[i][6], acc[i][7]);
        p1.x = pack2bf(acc[i][8], acc[i][9]);
        p1.y = pack2bf(acc[i][10], acc[i][11]);
        p1.z = pack2bf(acc[i][12], acc[i][13]);
        p1.w = pack2bf(acc[i][14], acc[i][15]);
        *(uint4*)(orow + 0) = p0;
        *(uint4*)(orow + 8) = p1;
    }
}

// ---------------------------------------------------------------------------
// CSR build, contention-free. 196 tiles (was 98: only 38% of CUs busy).
// ---------------------------------------------------------------------------
__global__ __launch_bounds__(256) void bin_hist(const int* __restrict__ dst,
                                                int* __restrict__ bcnt) {
    int tile = tile_of(blockIdx.x);
    int beg = tile * TILE_E, end = min(beg + TILE_E, N_EDGES);
    __shared__ int cnt[NBUK];
    for (int b = threadIdx.x; b < NBUK; b += 256) cnt[b] = 0;
    __syncthreads();
    for (int i = beg + threadIdx.x * 4; i < end; i += 256 * 4) {
        int4 d = *(const int4*)(dst + i);
        atomicAdd(&cnt[d.x >> BSHIFT], 1);
        atomicAdd(&cnt[d.y >> BSHIFT], 1);
        atomicAdd(&cnt[d.z >> BSHIFT], 1);
        atomicAdd(&cnt[d.w >> BSHIFT], 1);
    }
    __syncthreads();
    for (int b = threadIdx.x; b < NBUK; b += 256) bcnt[(size_t)b * NBLK_E + tile] = cnt[b];
}

__global__ __launch_bounds__(256) void bin_scanA(const int* __restrict__ bcnt,
                                                 int* __restrict__ boff,
                                                 int* __restrict__ btot) {
    int bin = blockIdx.x, t = threadIdx.x;
    __shared__ int tmp[256];
    int v = (t < NBLK_E) ? bcnt[(size_t)bin * NBLK_E + t] : 0;
    tmp[t] = v;
    __syncthreads();
    for (int off = 1; off < 256; off <<= 1) {
        int a = (t >= off) ? tmp[t - off] : 0;
        __syncthreads();
        tmp[t] += a;
        __syncthreads();
    }
    if (t < NBLK_E) boff[(size_t)bin * NBLK_E + t] = tmp[t] - v;
    if (t == NBLK_E - 1) btot[bin] = tmp[t];
}

// generic 782-entry exclusive scan; sentinel >= 0 -> out[NBUK] = sentinel
__global__ __launch_bounds__(1024) void exscan782(const int* __restrict__ in,
                                                  int* __restrict__ out,
                                                  int sentinel) {
    int t = threadIdx.x;
    __shared__ int tmp[1024];
    int v = (t < NBUK) ? in[t] : 0;
    tmp[t] = v;
    __syncthreads();
    for (int off = 1; off < 1024; off <<= 1) {
        int a = (t >= off) ? tmp[t - off] : 0;
        __syncthreads();
        tmp[t] += a;
        __syncthreads();
    }
    if (t < NBUK) out[t] = tmp[t] - v;
    if (t == 0 && sentinel >= 0) out[NBUK] = sentinel;
}

__global__ __launch_bounds__(256) void bin_scatter(const int* __restrict__ src,
                                                   const int* __restrict__ dst,
                                                   const int* __restrict__ bbase,
                                                   const int* __restrict__ boff,
                                                   int* __restrict__ ebuf) {
    int tile = tile_of(blockIdx.x);
    int beg = tile * TILE_E, end = min(beg + TILE_E, N_EDGES);
    __shared__ int curs[NBUK];
    for (int b = threadIdx.x; b < NBUK; b += 256)
        curs[b] = bbase[b] + boff[(size_t)b * NBLK_E + tile];
    __syncthreads();
    for (int i = beg + threadIdx.x * 4; i < end; i += 256 * 4) {
        int4 d = *(const int4*)(dst + i);
        int4 s = *(const int4*)(src + i);
#pragma unroll
        for (int e = 0; e < 4; ++e) {
            int dv = e == 0 ? d.x : e == 1 ? d.y : e == 2 ? d.z : d.w;
            int sv = e == 0 ? s.x : e == 1 ? s.y : e == 2 ? s.z : s.w;
            int p = atomicAdd(&curs[dv >> BSHIFT], 1);  // LDS atomic: cheap
            ebuf[p] = (sv << BSHIFT) | (dv & (BNODES - 1));
        }
    }
}

// per-bucket: degree count from the contiguous run + bucket total (fused
// block-sum replaces the old scan_blocksum pass over deg).
__global__ __launch_bounds__(256) void bucket_hist(const int* __restrict__ ebuf,
                                                   const int* __restrict__ bbase,
                                                   int* __restrict__ deg,
                                                   int* __restrict__ bsumsB) {
    int b = blockIdx.x;
    int lo = b << BSHIFT;
    __shared__ int cnt[BNODES];
    if (threadIdx.x < BNODES) cnt[threadIdx.x] = 0;
    __syncthreads();
    int beg = bbase[b], end = bbase[b + 1];
    for (int i = beg + threadIdx.x; i < end; i += 256)
        atomicAdd(&cnt[ebuf[i] & (BNODES - 1)], 1);
    __syncthreads();
    if (threadIdx.x < BNODES && lo + threadIdx.x < N_NODES)
        deg[lo + threadIdx.x] = cnt[threadIdx.x];
    // tree-reduce cnt -> bucket total (safe: deg already written)
    if (threadIdx.x < 64) cnt[threadIdx.x] += cnt[threadIdx.x + 64];
    __syncthreads();
    if (threadIdx.x < 32) cnt[threadIdx.x] += cnt[threadIdx.x + 32];
    __syncthreads();
    if (threadIdx.x < 16) cnt[threadIdx.x] += cnt[threadIdx.x + 16];
    __syncthreads();
    if (threadIdx.x == 0) {
        int s = 0;
        for (int i = 0; i < 16; ++i) s += cnt[i];
        bsumsB[b] = s;
    }
}

// per-bucket exclusive scan of deg -> rp (boffs gives the bucket's base)
__global__ __launch_bounds__(128) void scan_final(const int* __restrict__ deg,
                                                  const int* __restrict__ boffs,
                                                  int* __restrict__ rp) {
    int b = blockIdx.x, t = threadIdx.x;
    int i = b * BNODES + t;
    int val = (i < N_NODES) ? deg[i] : 0;
    __shared__ int tmp[BNODES];
    tmp[t] = val;
    __syncthreads();
    for (int off = 1; off < BNODES; off <<= 1) {
        int a = (t >= off) ? tmp[t - off] : 0;
        __syncthreads();
        tmp[t] += a;
        __syncthreads();
    }
    int excl = tmp[t] - val + boffs[b];
    if (i < N_NODES) {
        rp[i] = excl;
        if (i == N_NODES - 1) rp[N_NODES] = excl + val;
    }
}

__global__ __launch_bounds__(256) void bucket_place(const int* __restrict__ ebuf,
                                                    const int* __restrict__ bbase,
                                                    const int* __restrict__ rp,
                                                    int* __restrict__ cols) {
    int b = blockIdx.x;
    int lo = b << BSHIFT;
    __shared__ int cur[BNODES];
    if (threadIdx.x < BNODES)
        cur[threadIdx.x] = (lo + threadIdx.x < N_NODES) ? rp[lo + threadIdx.x] : 0;
    __syncthreads();
    int beg = bbase[b], end = bbase[b + 1];
    for (int i = beg + threadIdx.x; i < end; i += 256) {
        int v = ebuf[i];
        int p = atomicAdd(&cur[v & (BNODES - 1)], 1);
        cols[p] = v >> BSHIFT;
    }
}

// ---------------------------------------------------------------------------
// Gather + fused BN stats, 24 lanes/node x 8 B (ushort4 = 4 bf16):
// round-9 shape (2x the VMEM instructions in flight of the 12-lane form --
// this kernel is L3-latency-bound, MLP wins) + bf16 z write (uint2).
// ---------------------------------------------------------------------------
#define GLANES 24
#define GNODES 8  // 192 threads / 24 lanes

__global__ __launch_bounds__(192) void gather_stats(const ushort* __restrict__ T,
                                                    const int* __restrict__ rp,
                                                    const int* __restrict__ cols,
                                                    const float* __restrict__ bias,
                                                    ushort* __restrict__ z,
                                                    float* __restrict__ psums,
                                                    float* __restrict__ psq) {
    const int q = threadIdx.x % GLANES;   // 4-column chunk
    const int rs = threadIdx.x / GLANES;  // node slot 0..7
    const float4 bias4 = ((const float4*)bias)[q];
    float4 s = make_float4(0.f, 0.f, 0.f, 0.f);
    float4 sq = make_float4(0.f, 0.f, 0.f, 0.f);

#define ADDROW(u)                                                              \
    {                                                                          \
        ushort4 w = *(const ushort4*)(T + (size_t)(u) * HID + q * 4);          \
        a.x += bf2f(w.x); a.y += bf2f(w.y);                                    \
        a.z += bf2f(w.z); a.w += bf2f(w.w);                                    \
    }

    for (int v = blockIdx.x * GNODES + rs; v < N_NODES; v += NB_GATH * GNODES) {
        float4 a = bias4;
        ADDROW(v);
        int beg = rp[v], end = rp[v + 1];
        int j = beg;
        for (; j + 3 < end; j += 4) {
            int u0 = cols[j], u1 = cols[j + 1], u2 = cols[j + 2], u3 = cols[j + 3];
            ADDROW(u0); ADDROW(u1); ADDROW(u2); ADDROW(u3);
        }
        for (; j < end; ++j) ADDROW(cols[j]);

        uint2 o;
        o.x = pack2bf(a.x, a.y);
        o.y = pack2bf(a.z, a.w);
        *(uint2*)(z + (size_t)v * HID + q * 4) = o;
        s.x += a.x; s.y += a.y; s.z += a.z; s.w += a.w;
        sq.x = fmaf(a.x, a.x, sq.x);
        sq.y = fmaf(a.y, a.y, sq.y);
        sq.z = fmaf(a.z, a.z, sq.z);
        sq.w = fmaf(a.w, a.w, sq.w);
    }
#undef ADDROW

    __shared__ float4 ls[GNODES][GLANES], lq[GNODES][GLANES];
    ls[rs][q] = s;
    lq[rs][q] = sq;
    __syncthreads();
    if (threadIdx.x < GLANES) {
        float4 S = ls[0][threadIdx.x], Q = lq[0][threadIdx.x];
#pragma unroll
        for (int i = 1; i < GNODES; ++i) {
            S.x += ls[i][threadIdx.x].x; S.y += ls[i][threadIdx.x].y;
            S.z += ls[i][threadIdx.x].z; S.w += ls[i][threadIdx.x].w;
            Q.x += lq[i][threadIdx.x].x; Q.y += lq[i][threadIdx.x].y;
            Q.z += lq[i][threadIdx.x].z; Q.w += lq[i][threadIdx.x].w;
        }
        ((float4*)(psums + (size_t)blockIdx.x * HID))[threadIdx.x] = S;
        ((float4*)(psq + (size_t)blockIdx.x * HID))[threadIdx.x] = Q;
    }
}

// ---------------------------------------------------------------------------
__global__ __launch_bounds__(384) void bn_finalize(const float* __restrict__ psums,
                                                   const float* __restrict__ psq,
                                                   const float* __restrict__ g,
                                                   const float* __restrict__ be,
                                                   float* __restrict__ scale,
                                                   float* __restrict__ shift) {
    int c = threadIdx.x % 96, h = threadIdx.x / 96;
    float S = 0.f, Q = 0.f;
    for (int b = h * (NB_GATH / 4); b < (h + 1) * (NB_GATH / 4); ++b) {
        S += psums[(size_t)b * HID + c];
        Q += psq[(size_t)b * HID + c];
    }
    __shared__ float lS[4][96], lQ[4][96];
    lS[h][c] = S;
    lQ[h][c] = Q;
    __syncthreads();
    if (threadIdx.x < 96) {
        S = lS[0][c] + lS[1][c] + lS[2][c] + lS[3][c];
        Q = lQ[0][c] + lQ[1][c] + lQ[2][c] + lQ[3][c];
        float mu = S * (1.0f / N_NODES);
        float var = Q * (1.0f / N_NODES) - mu * mu;
        float rstd = rsqrtf(var + 1e-5f);
        float sc = g[c] * rstd;
        scale[c] = sc;
        shift[c] = be[c] - mu * sc;
    }
}

// ---------------------------------------------------------------------------
// Readout: bf16 input, BN2+ReLU fused during LDS staging, 16 lanes/row
// shuffle log_softmax, coalesced store.
// ---------------------------------------------------------------------------
__global__ __launch_bounds__(256) void readout_kernel(const ushort* __restrict__ X,
                                                      const float* __restrict__ scale,
                                                      const float* __restrict__ shift,
                                                      const float* __restrict__ Wr,
                                                      const float* __restrict__ br,
                                                      float* __restrict__ out) {
    __shared__ float Ws[HID * NCLS];
    __shared__ float XL[16 * 97];
    __shared__ float scs[HID], shs[HID], bs[NCLS];
    for (int i = threadIdx.x; i < HID * NCLS / 4; i += 256)
        ((float4*)Ws)[i] = ((const float4*)Wr)[i];
    if (threadIdx.x < HID) {
        scs[threadIdx.x] = scale[threadIdx.x];
        shs[threadIdx.x] = shift[threadIdx.x];
    }
    if (threadIdx.x < NCLS) bs[threadIdx.x] = br[threadIdx.x];

    int rr = threadIdx.x >> 4, t = threadIdx.x & 15;
    for (int tile = blockIdx.x; tile < N_NODES / 16; tile += gridDim.x) {
        int rbase = tile * 16;
        __syncthreads();
        if (threadIdx.x < 192) {  // 16 rows x 96 cols / 8 per thread
            int base = threadIdx.x * 8;
            int row = base / HID, col = base - (base / HID) * HID;
            uint4 w = *(const uint4*)(X + (size_t)rbase * HID + base);
            float v[8] = {bf_lo(w.x), bf_hi(w.x), bf_lo(w.y), bf_hi(w.y),
                          bf_lo(w.z), bf_hi(w.z), bf_lo(w.w), bf_hi(w.w)};
#pragma unroll
            for (int e = 0; e < 8; ++e)
                XL[row * 97 + col + e] = fmaxf(fmaf(v[e], scs[col + e], shs[col + e]), 0.f);
        }
        __syncthreads();
        float acc = bs[t];
        const float* xrow = &XL[rr * 97];
#pragma unroll 4
        for (int k = 0; k < HID; ++k) acc = fmaf(xrow[k], Ws[k * NCLS + t], acc);
        float m = acc;
#pragma unroll
        for (int off = 8; off; off >>= 1) m = fmaxf(m, __shfl_xor(m, off, 16));
        float e = expf(acc - m);
        float sum = e;
#pragma unroll
        for (int off = 8; off; off >>= 1) sum += __shfl_xor(sum, off, 16);
        float lse = m + logf(sum);
        out[(size_t)rbase * NCLS + threadIdx.x] = acc - lse;
    }
}

// ---------------------------------------------------------------------------
extern "C" void kernel_launch(void* const* d_in, const int* in_sizes, int n_in,
                              void* d_out, int out_size, void* d_ws, size_t ws_size,
                              hipStream_t stream) {
    const float* h     = (const float*)d_in[0];
    const int*   src   = (const int*)d_in[1];
    const int*   dst   = (const int*)d_in[2];
    const float* W_emb = (const float*)d_in[3];
    const float* b_emb = (const float*)d_in[4];
    const float* W1    = (const float*)d_in[5];
    const float* b1    = (const float*)d_in[6];
    const float* g1    = (const float*)d_in[7];
    const float* be1   = (const float*)d_in[8];
    const float* W2    = (const float*)d_in[9];
    const float* b2    = (const float*)d_in[10];
    const float* g2    = (const float*)d_in[11];
    const float* be2   = (const float*)d_in[12];
    const float* Wr    = (const float*)d_in[13];
    const float* br    = (const float*)d_in[14];

    const size_t nh = (size_t)N_NODES * HID;
    ushort* z    = (ushort*)d_ws;             // 19.2 MB bf16 (z1, then z2)
    ushort* T    = z + nh;                    // 19.2 MB bf16 table
    int* deg     = (int*)(T + nh);            // N
    int* rp      = deg + N_NODES;             // N+1
    int* cols    = rp + N_NODES + 1;          // E (6.4 MB)
    int* ebuf    = cols + N_EDGES;            // E (6.4 MB, bucket-sorted packed)
    int* bcnt    = ebuf + N_EDGES;            // NBUK*NBLK_E
    int* boff    = bcnt + NBUK * NBLK_E;      // NBUK*NBLK_E
    int* btot    = boff + NBUK * NBLK_E;      // NBUK
    int* bbase   = btot + NBUK;               // NBUK+1
    int* bsumsB  = bbase + NBUK + 1;          // NBUK
    int* boffs   = bsumsB + NBUK;             // NBUK
    float* psums = (float*)(boffs + NBUK);    // NB_GATH*96
    float* psq   = psums + (size_t)NB_GATH * HID;
    float* scale = psq + (size_t)NB_GATH * HID;   // 96
    float* shift = scale + HID;                    // 96
    float* Wf    = shift + HID;                    // 128*96
    float* bf    = Wf + IN_DIM * HID;              // 96

    const int blkT = (N_NODES + 63) / 64;     // 1563

    // --- CSR build: tile-hist -> scans -> deterministic scatter -> place ---
    bin_hist<<<NBLK_E, 256, 0, stream>>>(dst, bcnt);
    bin_scanA<<<NBUK, 256, 0, stream>>>(bcnt, boff, btot);
    exscan782<<<1, 1024, 0, stream>>>(btot, bbase, N_EDGES);
    bin_scatter<<<NBLK_E, 256, 0, stream>>>(src, dst, bbase, boff, ebuf);
    bucket_hist<<<NBUK, 256, 0, stream>>>(ebuf, bbase, deg, bsumsB);
    exscan782<<<1, 1024, 0, stream>>>(bsumsB, boffs, -1);
    scan_final<<<NBUK, 128, 0, stream>>>(deg, boffs, rp);
    bucket_place<<<NBUK, 256, 0, stream>>>(ebuf, bbase, rp, cols);
    wfuse<<<(IN_DIM * HID + 255) / 256, 256, 0, stream>>>(W_emb, W1, b_emb, Wf, bf);

    // --- layer 1: T1 = h @ Wf + bf (bf16);  z1 = gather(T1) + b1 (+stats) ---
    gemm_l1<<<blkT, 192, 0, stream>>>(h, Wf, bf, T);
    gather_stats<<<NB_GATH, 192, 0, stream>>>(T, rp, cols, b1, z, psums, psq);
    bn_finalize<<<1, 384, 0, stream>>>(psums, psq, g1, be1, scale, shift);

    // --- layer 2: T2 = relu(bn1(z1)) @ W2 (bf16);  z2 = gather(T2) + b2 ---
    gemm_l2<<<blkT, 192, 0, stream>>>(z, W2, scale, shift, T);
    gather_stats<<<NB_GATH, 192, 0, stream>>>(T, rp, cols, b2, z, psums, psq);
    bn_finalize<<<1, 384, 0, stream>>>(psums, psq, g2, be2, scale, shift);

    // --- readout (BN2+ReLU fused) + log_softmax ---
    readout_kernel<<<2048, 256, 0, stream>>>(z, scale, shift, Wr, br, (float*)d_out);
}

// Round 13
// 323.354 us; speedup vs baseline: 1.1964x; 1.1703x over previous
//
#include <hip/hip_runtime.h>
#include <cmath>

#define N_NODES 100000
#define N_EDGES 1600000
#define IN_DIM 128
#define HID 96
#define NCLS 16
#define NB_GATH 2048  // gather grid (fixed, for stats partials)

// bucket-sort CSR build (contention-free)
#define BSHIFT 7
#define BNODES 128                 // nodes per bucket
#define NBUK 782                   // ceil(N_NODES/128)
#define TILE_E 8192                // edges per tile
#define NBLK_E 196                 // ceil(N_EDGES/TILE_E)
#define NBLK_Q 24                  // NBLK_E/8
#define NBLK_R 4                   // NBLK_E%8

typedef unsigned int uint;
typedef unsigned short ushort;
typedef __attribute__((ext_vector_type(8))) short short8v;   // 8 bf16 (4 VGPRs)
typedef __attribute__((ext_vector_type(4))) float float4v;   // MFMA acc

__device__ __forceinline__ ushort f2bf(float x) {  // RNE f32->bf16
    uint b = __float_as_uint(x);
    uint r = (b + 0x7FFFu + ((b >> 16) & 1u)) >> 16;
    return (ushort)r;
}
__device__ __forceinline__ float bf2f(ushort u) {
    return __uint_as_float(((uint)u) << 16);
}
__device__ __forceinline__ float bf_lo(uint w) { return __uint_as_float(w << 16); }
__device__ __forceinline__ float bf_hi(uint w) { return __uint_as_float(w & 0xFFFF0000u); }
__device__ __forceinline__ uint pack2bf(float a, float b) {
    return (uint)f2bf(a) | ((uint)f2bf(b) << 16);
}

// XCD-swizzled tile mapping (bijective for NBLK_E = 8*NBLK_Q + NBLK_R).
__device__ __forceinline__ int tile_of(int blk) {
    int xcd = blk & 7, slot = blk >> 3;
    return (xcd < NBLK_R) ? xcd * (NBLK_Q + 1) + slot
                          : NBLK_R * (NBLK_Q + 1) + (xcd - NBLK_R) * NBLK_Q + slot;
}

// ---------------------------------------------------------------------------
// wfuse: Wf[128][96] = W_emb @ W1 ; bf[96] = b_emb @ W1
// ---------------------------------------------------------------------------
__global__ __launch_bounds__(256) void wfuse(const float* __restrict__ W_emb,
                                             const float* __restrict__ W1,
                                             const float* __restrict__ b_emb,
                                             float* __restrict__ Wf,
                                             float* __restrict__ bf) {
    __shared__ float W1s[HID * HID];
    for (int i = threadIdx.x; i < HID * HID / 4; i += 256)
        ((float4*)W1s)[i] = ((const float4*)W1)[i];
    __syncthreads();
    int idx = blockIdx.x * 256 + threadIdx.x;
    if (idx < IN_DIM * HID) {
        int i = idx / HID, j = idx - (idx / HID) * HID;
        float acc = 0.f;
        for (int k = 0; k < HID; ++k)
            acc = fmaf(W_emb[(size_t)i * HID + k], W1s[k * HID + j], acc);
        Wf[idx] = acc;
    }
    if (idx < HID) {
        float acc = 0.f;
        for (int k = 0; k < HID; ++k)
            acc = fmaf(b_emb[k], W1s[k * HID + idx], acc);
        bf[idx] = acc;
    }
}

// ---------------------------------------------------------------------------
// MFMA layer-1 GEMM: T1 = bf16(X) @ Wf + bf -> bf16 table.
// 384 thr = 6 waves x 16-row tiles = 96 rows/block. A staged bf16 in LDS
// [96][K+8] (pad: frag ds_read_b128 ~2-way banked); W staged TRANSPOSED
// W_t[96][K+8] so one B-fragment = one ds_read_b128. Per wave:
// K/32 x (1 A-read + 6 x (B-read + v_mfma_f32_16x16x32_bf16)).
// Frag layouts (guide-verified): A row=lane&15,k=(lane>>4)*8+e;
// B col=lane&15,same k; D col=lane&15,row=(lane>>4)*4+reg.
// ---------------------------------------------------------------------------
__global__ __launch_bounds__(384) void gemm_l1(const float* __restrict__ X,
                                               const float* __restrict__ W,
                                               const float* __restrict__ bias,
                                               ushort* __restrict__ outB) {
    constexpr int K = IN_DIM, KPAD = K + 8;
    __shared__ ushort A_s[96 * KPAD];
    __shared__ ushort W_t[96 * KPAD];
    __shared__ float bs[HID];
    if (threadIdx.x < HID) bs[threadIdx.x] = bias[threadIdx.x];

    const int rbase = blockIdx.x * 96;
    // stage A: 96 rows x 128 k, 8 f32 -> packed 8 bf16 (uint4) per chunk
    for (int c = threadIdx.x; c < 96 * (K / 8); c += 384) {
        int row = c / (K / 8), ko = (c - row * (K / 8)) * 8;
        int gr = min(rbase + row, N_NODES - 1);
        const float* xp = X + (size_t)gr * K + ko;
        float4 v0 = *(const float4*)xp;
        float4 v1 = *(const float4*)(xp + 4);
        uint4 p;
        p.x = pack2bf(v0.x, v0.y);
        p.y = pack2bf(v0.z, v0.w);
        p.z = pack2bf(v1.x, v1.y);
        p.w = pack2bf(v1.z, v1.w);
        *(uint4*)&A_s[row * KPAD + ko] = p;
    }
    // stage W transposed: W_t[n][k] = bf16(W[k][n])
    for (int j = threadIdx.x; j < K * HID; j += 384) {
        int k = j / HID, n = j - k * HID;
        W_t[n * KPAD + k] = f2bf(W[j]);
    }
    __syncthreads();

    const int lane = threadIdx.x & 63, w = threadIdx.x >> 6;
    const int ar = lane & 15, kg = lane >> 4;
    float4v acc[6] = {};
    const ushort* ap = &A_s[(w * 16 + ar) * KPAD + kg * 8];
    const ushort* bp = &W_t[ar * KPAD + kg * 8];
#pragma unroll
    for (int kc = 0; kc < K / 32; ++kc) {
        short8v af = *(const short8v*)(ap + kc * 32);
#pragma unroll
        for (int ct = 0; ct < 6; ++ct) {
            short8v bfv = *(const short8v*)(bp + ct * 16 * KPAD + kc * 32);
            acc[ct] = __builtin_amdgcn_mfma_f32_16x16x32_bf16(af, bfv, acc[ct], 0, 0, 0);
        }
    }
#pragma unroll
    for (int ct = 0; ct < 6; ++ct) {
        int col = ct * 16 + ar;
        float bb = bs[col];
#pragma unroll
        for (int i = 0; i < 4; ++i) {
            int grow = rbase + w * 16 + kg * 4 + i;
            if (grow < N_NODES)
                outB[(size_t)grow * HID + col] = f2bf(acc[ct][i] + bb);
        }
    }
}

// ---------------------------------------------------------------------------
// MFMA layer-2 GEMM: T2 = relu(bn1(z1)) @ W2 -> bf16 (BN+ReLU at A-staging).
// K=96, KPAD=104; LDS 40.7 KB.
// ---------------------------------------------------------------------------
__global__ __launch_bounds__(384) void gemm_l2(const ushort* __restrict__ X,
                                               const float* __restrict__ W,
                                               const float* __restrict__ scale,
                                               const float* __restrict__ shift,
                                               ushort* __restrict__ outB) {
    constexpr int K = HID, KPAD = K + 8;
    __shared__ ushort A_s[96 * KPAD];
    __shared__ ushort W_t[96 * KPAD];
    __shared__ float scs[HID], shs[HID];
    if (threadIdx.x < HID) {
        scs[threadIdx.x] = scale[threadIdx.x];
        shs[threadIdx.x] = shift[threadIdx.x];
    }
    __syncthreads();  // scs/shs visible before A staging

    const int rbase = blockIdx.x * 96;
    for (int c = threadIdx.x; c < 96 * (K / 8); c += 384) {
        int row = c / (K / 8), ko = (c - row * (K / 8)) * 8;
        int gr = min(rbase + row, N_NODES - 1);
        uint4 u = *(const uint4*)(X + (size_t)gr * K + ko);
        float4 sA = *(const float4*)&scs[ko], sB = *(const float4*)&scs[ko + 4];
        float4 hA = *(const float4*)&shs[ko], hB = *(const float4*)&shs[ko + 4];
        float v0 = fmaxf(fmaf(bf_lo(u.x), sA.x, hA.x), 0.f);
        float v1 = fmaxf(fmaf(bf_hi(u.x), sA.y, hA.y), 0.f);
        float v2 = fmaxf(fmaf(bf_lo(u.y), sA.z, hA.z), 0.f);
        float v3 = fmaxf(fmaf(bf_hi(u.y), sA.w, hA.w), 0.f);
        float v4 = fmaxf(fmaf(bf_lo(u.z), sB.x, hB.x), 0.f);
        float v5 = fmaxf(fmaf(bf_hi(u.z), sB.y, hB.y), 0.f);
        float v6 = fmaxf(fmaf(bf_lo(u.w), sB.z, hB.z), 0.f);
        float v7 = fmaxf(fmaf(bf_hi(u.w), sB.w, hB.w), 0.f);
        uint4 p;
        p.x = pack2bf(v0, v1);
        p.y = pack2bf(v2, v3);
        p.z = pack2bf(v4, v5);
        p.w = pack2bf(v6, v7);
        *(uint4*)&A_s[row * KPAD + ko] = p;
    }
    for (int j = threadIdx.x; j < K * HID; j += 384) {
        int k = j / HID, n = j - k * HID;
        W_t[n * KPAD + k] = f2bf(W[j]);
    }
    __syncthreads();

    const int lane = threadIdx.x & 63, w = threadIdx.x >> 6;
    const int ar = lane & 15, kg = lane >> 4;
    float4v acc[6] = {};
    const ushort* ap = &A_s[(w * 16 + ar) * KPAD + kg * 8];
    const ushort* bp = &W_t[ar * KPAD + kg * 8];
#pragma unroll
    for (int kc = 0; kc < K / 32; ++kc) {
        short8v af = *(const short8v*)(ap + kc * 32);
#pragma unroll
        for (int ct = 0; ct < 6; ++ct) {
            short8v bfv = *(const short8v*)(bp + ct * 16 * KPAD + kc * 32);
            acc[ct] = __builtin_amdgcn_mfma_f32_16x16x32_bf16(af, bfv, acc[ct], 0, 0, 0);
        }
    }
#pragma unroll
    for (int ct = 0; ct < 6; ++ct) {
        int col = ct * 16 + ar;
#pragma unroll
        for (int i = 0; i < 4; ++i) {
            int grow = rbase + w * 16 + kg * 4 + i;
            if (grow < N_NODES)
                outB[(size_t)grow * HID + col] = f2bf(acc[ct][i]);
        }
    }
}

// ---------------------------------------------------------------------------
// CSR build, contention-free (unchanged from round 12).
// ---------------------------------------------------------------------------
__global__ __launch_bounds__(256) void bin_hist(const int* __restrict__ dst,
                                                int* __restrict__ bcnt) {
    int tile = tile_of(blockIdx.x);
    int beg = tile * TILE_E, end = min(beg + TILE_E, N_EDGES);
    __shared__ int cnt[NBUK];
    for (int b = threadIdx.x; b < NBUK; b += 256) cnt[b] = 0;
    __syncthreads();
    for (int i = beg + threadIdx.x * 4; i < end; i += 256 * 4) {
        int4 d = *(const int4*)(dst + i);
        atomicAdd(&cnt[d.x >> BSHIFT], 1);
        atomicAdd(&cnt[d.y >> BSHIFT], 1);
        atomicAdd(&cnt[d.z >> BSHIFT], 1);
        atomicAdd(&cnt[d.w >> BSHIFT], 1);
    }
    __syncthreads();
    for (int b = threadIdx.x; b < NBUK; b += 256) bcnt[(size_t)b * NBLK_E + tile] = cnt[b];
}

__global__ __launch_bounds__(256) void bin_scanA(const int* __restrict__ bcnt,
                                                 int* __restrict__ boff,
                                                 int* __restrict__ btot) {
    int bin = blockIdx.x, t = threadIdx.x;
    __shared__ int tmp[256];
    int v = (t < NBLK_E) ? bcnt[(size_t)bin * NBLK_E + t] : 0;
    tmp[t] = v;
    __syncthreads();
    for (int off = 1; off < 256; off <<= 1) {
        int a = (t >= off) ? tmp[t - off] : 0;
        __syncthreads();
        tmp[t] += a;
        __syncthreads();
    }
    if (t < NBLK_E) boff[(size_t)bin * NBLK_E + t] = tmp[t] - v;
    if (t == NBLK_E - 1) btot[bin] = tmp[t];
}

// generic 782-entry exclusive scan; sentinel >= 0 -> out[NBUK] = sentinel
__global__ __launch_bounds__(1024) void exscan782(const int* __restrict__ in,
                                                  int* __restrict__ out,
                                                  int sentinel) {
    int t = threadIdx.x;
    __shared__ int tmp[1024];
    int v = (t < NBUK) ? in[t] : 0;
    tmp[t] = v;
    __syncthreads();
    for (int off = 1; off < 1024; off <<= 1) {
        int a = (t >= off) ? tmp[t - off] : 0;
        __syncthreads();
        tmp[t] += a;
        __syncthreads();
    }
    if (t < NBUK) out[t] = tmp[t] - v;
    if (t == 0 && sentinel >= 0) out[NBUK] = sentinel;
}

__global__ __launch_bounds__(256) void bin_scatter(const int* __restrict__ src,
                                                   const int* __restrict__ dst,
                                                   const int* __restrict__ bbase,
                                                   const int* __restrict__ boff,
                                                   int* __restrict__ ebuf) {
    int tile = tile_of(blockIdx.x);
    int beg = tile * TILE_E, end = min(beg + TILE_E, N_EDGES);
    __shared__ int curs[NBUK];
    for (int b = threadIdx.x; b < NBUK; b += 256)
        curs[b] = bbase[b] + boff[(size_t)b * NBLK_E + tile];
    __syncthreads();
    for (int i = beg + threadIdx.x * 4; i < end; i += 256 * 4) {
        int4 d = *(const int4*)(dst + i);
        int4 s = *(const int4*)(src + i);
#pragma unroll
        for (int e = 0; e < 4; ++e) {
            int dv = e == 0 ? d.x : e == 1 ? d.y : e == 2 ? d.z : d.w;
            int sv = e == 0 ? s.x : e == 1 ? s.y : e == 2 ? s.z : s.w;
            int p = atomicAdd(&curs[dv >> BSHIFT], 1);  // LDS atomic: cheap
            ebuf[p] = (sv << BSHIFT) | (dv & (BNODES - 1));
        }
    }
}

// per-bucket: degree count from the contiguous run + bucket total
__global__ __launch_bounds__(256) void bucket_hist(const int* __restrict__ ebuf,
                                                   const int* __restrict__ bbase,
                                                   int* __restrict__ deg,
                                                   int* __restrict__ bsumsB) {
    int b = blockIdx.x;
    int lo = b << BSHIFT;
    __shared__ int cnt[BNODES];
    if (threadIdx.x < BNODES) cnt[threadIdx.x] = 0;
    __syncthreads();
    int beg = bbase[b], end = bbase[b + 1];
    for (int i = beg + threadIdx.x; i < end; i += 256)
        atomicAdd(&cnt[ebuf[i] & (BNODES - 1)], 1);
    __syncthreads();
    if (threadIdx.x < BNODES && lo + threadIdx.x < N_NODES)
        deg[lo + threadIdx.x] = cnt[threadIdx.x];
    if (threadIdx.x < 64) cnt[threadIdx.x] += cnt[threadIdx.x + 64];
    __syncthreads();
    if (threadIdx.x < 32) cnt[threadIdx.x] += cnt[threadIdx.x + 32];
    __syncthreads();
    if (threadIdx.x < 16) cnt[threadIdx.x] += cnt[threadIdx.x + 16];
    __syncthreads();
    if (threadIdx.x == 0) {
        int s = 0;
        for (int i = 0; i < 16; ++i) s += cnt[i];
        bsumsB[b] = s;
    }
}

// per-bucket exclusive scan of deg -> rp
__global__ __launch_bounds__(128) void scan_final(const int* __restrict__ deg,
                                                  const int* __restrict__ boffs,
                                                  int* __restrict__ rp) {
    int b = blockIdx.x, t = threadIdx.x;
    int i = b * BNODES + t;
    int val = (i < N_NODES) ? deg[i] : 0;
    __shared__ int tmp[BNODES];
    tmp[t] = val;
    __syncthreads();
    for (int off = 1; off < BNODES; off <<= 1) {
        int a = (t >= off) ? tmp[t - off] : 0;
        __syncthreads();
        tmp[t] += a;
        __syncthreads();
    }
    int excl = tmp[t] - val + boffs[b];
    if (i < N_NODES) {
        rp[i] = excl;
        if (i == N_NODES - 1) rp[N_NODES] = excl + val;
    }
}

__global__ __launch_bounds__(256) void bucket_place(const int* __restrict__ ebuf,
                                                    const int* __restrict__ bbase,
                                                    const int* __restrict__ rp,
                                                    int* __restrict__ cols) {
    int b = blockIdx.x;
    int lo = b << BSHIFT;
    __shared__ int cur[BNODES];
    if (threadIdx.x < BNODES)
        cur[threadIdx.x] = (lo + threadIdx.x < N_NODES) ? rp[lo + threadIdx.x] : 0;
    __syncthreads();
    int beg = bbase[b], end = bbase[b + 1];
    for (int i = beg + threadIdx.x; i < end; i += 256) {
        int v = ebuf[i];
        int p = atomicAdd(&cur[v & (BNODES - 1)], 1);
        cols[p] = v >> BSHIFT;
    }
}

// ---------------------------------------------------------------------------
// Gather + fused BN stats, 24 lanes/node x 8 B (unchanged from round 12).
// ---------------------------------------------------------------------------
#define GLANES 24
#define GNODES 8  // 192 threads / 24 lanes

__global__ __launch_bounds__(192) void gather_stats(const ushort* __restrict__ T,
                                                    const int* __restrict__ rp,
                                                    const int* __restrict__ cols,
                                                    const float* __restrict__ bias,
                                                    ushort* __restrict__ z,
                                                    float* __restrict__ psums,
                                                    float* __restrict__ psq) {
    const int q = threadIdx.x % GLANES;   // 4-column chunk
    const int rs = threadIdx.x / GLANES;  // node slot 0..7
    const float4 bias4 = ((const float4*)bias)[q];
    float4 s = make_float4(0.f, 0.f, 0.f, 0.f);
    float4 sq = make_float4(0.f, 0.f, 0.f, 0.f);

#define ADDROW(u)                                                              \
    {                                                                          \
        ushort4 w = *(const ushort4*)(T + (size_t)(u) * HID + q * 4);          \
        a.x += bf2f(w.x); a.y += bf2f(w.y);                                    \
        a.z += bf2f(w.z); a.w += bf2f(w.w);                                    \
    }

    for (int v = blockIdx.x * GNODES + rs; v < N_NODES; v += NB_GATH * GNODES) {
        float4 a = bias4;
        ADDROW(v);
        int beg = rp[v], end = rp[v + 1];
        int j = beg;
        for (; j + 3 < end; j += 4) {
            int u0 = cols[j], u1 = cols[j + 1], u2 = cols[j + 2], u3 = cols[j + 3];
            ADDROW(u0); ADDROW(u1); ADDROW(u2); ADDROW(u3);
        }
        for (; j < end; ++j) ADDROW(cols[j]);

        uint2 o;
        o.x = pack2bf(a.x, a.y);
        o.y = pack2bf(a.z, a.w);
        *(uint2*)(z + (size_t)v * HID + q * 4) = o;
        s.x += a.x; s.y += a.y; s.z += a.z; s.w += a.w;
        sq.x = fmaf(a.x, a.x, sq.x);
        sq.y = fmaf(a.y, a.y, sq.y);
        sq.z = fmaf(a.z, a.z, sq.z);
        sq.w = fmaf(a.w, a.w, sq.w);
    }
#undef ADDROW

    __shared__ float4 ls[GNODES][GLANES], lq[GNODES][GLANES];
    ls[rs][q] = s;
    lq[rs][q] = sq;
    __syncthreads();
    if (threadIdx.x < GLANES) {
        float4 S = ls[0][threadIdx.x], Q = lq[0][threadIdx.x];
#pragma unroll
        for (int i = 1; i < GNODES; ++i) {
            S.x += ls[i][threadIdx.x].x; S.y += ls[i][threadIdx.x].y;
            S.z += ls[i][threadIdx.x].z; S.w += ls[i][threadIdx.x].w;
            Q.x += lq[i][threadIdx.x].x; Q.y += lq[i][threadIdx.x].y;
            Q.z += lq[i][threadIdx.x].z; Q.w += lq[i][threadIdx.x].w;
        }
        ((float4*)(psums + (size_t)blockIdx.x * HID))[threadIdx.x] = S;
        ((float4*)(psq + (size_t)blockIdx.x * HID))[threadIdx.x] = Q;
    }
}

// ---------------------------------------------------------------------------
__global__ __launch_bounds__(384) void bn_finalize(const float* __restrict__ psums,
                                                   const float* __restrict__ psq,
                                                   const float* __restrict__ g,
                                                   const float* __restrict__ be,
                                                   float* __restrict__ scale,
                                                   float* __restrict__ shift) {
    int c = threadIdx.x % 96, h = threadIdx.x / 96;
    float S = 0.f, Q = 0.f;
    for (int b = h * (NB_GATH / 4); b < (h + 1) * (NB_GATH / 4); ++b) {
        S += psums[(size_t)b * HID + c];
        Q += psq[(size_t)b * HID + c];
    }
    __shared__ float lS[4][96], lQ[4][96];
    lS[h][c] = S;
    lQ[h][c] = Q;
    __syncthreads();
    if (threadIdx.x < 96) {
        S = lS[0][c] + lS[1][c] + lS[2][c] + lS[3][c];
        Q = lQ[0][c] + lQ[1][c] + lQ[2][c] + lQ[3][c];
        float mu = S * (1.0f / N_NODES);
        float var = Q * (1.0f / N_NODES) - mu * mu;
        float rstd = rsqrtf(var + 1e-5f);
        float sc = g[c] * rstd;
        scale[c] = sc;
        shift[c] = be[c] - mu * sc;
    }
}

// ---------------------------------------------------------------------------
// Readout: bf16 input, BN2+ReLU fused during LDS staging, 16 lanes/row
// shuffle log_softmax, coalesced store.
// ---------------------------------------------------------------------------
__global__ __launch_bounds__(256) void readout_kernel(const ushort* __restrict__ X,
                                                      const float* __restrict__ scale,
                                                      const float* __restrict__ shift,
                                                      const float* __restrict__ Wr,
                                                      const float* __restrict__ br,
                                                      float* __restrict__ out) {
    __shared__ float Ws[HID * NCLS];
    __shared__ float XL[16 * 97];
    __shared__ float scs[HID], shs[HID], bs[NCLS];
    for (int i = threadIdx.x; i < HID * NCLS / 4; i += 256)
        ((float4*)Ws)[i] = ((const float4*)Wr)[i];
    if (threadIdx.x < HID) {
        scs[threadIdx.x] = scale[threadIdx.x];
        shs[threadIdx.x] = shift[threadIdx.x];
    }
    if (threadIdx.x < NCLS) bs[threadIdx.x] = br[threadIdx.x];

    int rr = threadIdx.x >> 4, t = threadIdx.x & 15;
    for (int tile = blockIdx.x; tile < N_NODES / 16; tile += gridDim.x) {
        int rbase = tile * 16;
        __syncthreads();
        if (threadIdx.x < 192) {  // 16 rows x 96 cols / 8 per thread
            int base = threadIdx.x * 8;
            int row = base / HID, col = base - (base / HID) * HID;
            uint4 w = *(const uint4*)(X + (size_t)rbase * HID + base);
            float v[8] = {bf_lo(w.x), bf_hi(w.x), bf_lo(w.y), bf_hi(w.y),
                          bf_lo(w.z), bf_hi(w.z), bf_lo(w.w), bf_hi(w.w)};
#pragma unroll
            for (int e = 0; e < 8; ++e)
                XL[row * 97 + col + e] = fmaxf(fmaf(v[e], scs[col + e], shs[col + e]), 0.f);
        }
        __syncthreads();
        float acc = bs[t];
        const float* xrow = &XL[rr * 97];
#pragma unroll 4
        for (int k = 0; k < HID; ++k) acc = fmaf(xrow[k], Ws[k * NCLS + t], acc);
        float m = acc;
#pragma unroll
        for (int off = 8; off; off >>= 1) m = fmaxf(m, __shfl_xor(m, off, 16));
        float e = expf(acc - m);
        float sum = e;
#pragma unroll
        for (int off = 8; off; off >>= 1) sum += __shfl_xor(sum, off, 16);
        float lse = m + logf(sum);
        out[(size_t)rbase * NCLS + threadIdx.x] = acc - lse;
    }
}

// ---------------------------------------------------------------------------
extern "C" void kernel_launch(void* const* d_in, const int* in_sizes, int n_in,
                              void* d_out, int out_size, void* d_ws, size_t ws_size,
                              hipStream_t stream) {
    const float* h     = (const float*)d_in[0];
    const int*   src   = (const int*)d_in[1];
    const int*   dst   = (const int*)d_in[2];
    const float* W_emb = (const float*)d_in[3];
    const float* b_emb = (const float*)d_in[4];
    const float* W1    = (const float*)d_in[5];
    const float* b1    = (const float*)d_in[6];
    const float* g1    = (const float*)d_in[7];
    const float* be1   = (const float*)d_in[8];
    const float* W2    = (const float*)d_in[9];
    const float* b2    = (const float*)d_in[10];
    const float* g2    = (const float*)d_in[11];
    const float* be2   = (const float*)d_in[12];
    const float* Wr    = (const float*)d_in[13];
    const float* br    = (const float*)d_in[14];

    const size_t nh = (size_t)N_NODES * HID;
    ushort* z    = (ushort*)d_ws;             // 19.2 MB bf16 (z1, then z2)
    ushort* T    = z + nh;                    // 19.2 MB bf16 table
    int* deg     = (int*)(T + nh);            // N
    int* rp      = deg + N_NODES;             // N+1
    int* cols    = rp + N_NODES + 1;          // E (6.4 MB)
    int* ebuf    = cols + N_EDGES;            // E (6.4 MB, bucket-sorted packed)
    int* bcnt    = ebuf + N_EDGES;            // NBUK*NBLK_E
    int* boff    = bcnt + NBUK * NBLK_E;      // NBUK*NBLK_E
    int* btot    = boff + NBUK * NBLK_E;      // NBUK
    int* bbase   = btot + NBUK;               // NBUK+1
    int* bsumsB  = bbase + NBUK + 1;          // NBUK
    int* boffs   = bsumsB + NBUK;             // NBUK
    float* psums = (float*)(boffs + NBUK);    // NB_GATH*96
    float* psq   = psums + (size_t)NB_GATH * HID;
    float* scale = psq + (size_t)NB_GATH * HID;   // 96
    float* shift = scale + HID;                    // 96
    float* Wf    = shift + HID;                    // 128*96
    float* bf    = Wf + IN_DIM * HID;              // 96

    const int blkT = (N_NODES + 95) / 96;     // 1042

    // --- CSR build: tile-hist -> scans -> deterministic scatter -> place ---
    bin_hist<<<NBLK_E, 256, 0, stream>>>(dst, bcnt);
    bin_scanA<<<NBUK, 256, 0, stream>>>(bcnt, boff, btot);
    exscan782<<<1, 1024, 0, stream>>>(btot, bbase, N_EDGES);
    bin_scatter<<<NBLK_E, 256, 0, stream>>>(src, dst, bbase, boff, ebuf);
    bucket_hist<<<NBUK, 256, 0, stream>>>(ebuf, bbase, deg, bsumsB);
    exscan782<<<1, 1024, 0, stream>>>(bsumsB, boffs, -1);
    scan_final<<<NBUK, 128, 0, stream>>>(deg, boffs, rp);
    bucket_place<<<NBUK, 256, 0, stream>>>(ebuf, bbase, rp, cols);
    wfuse<<<(IN_DIM * HID + 255) / 256, 256, 0, stream>>>(W_emb, W1, b_emb, Wf, bf);

    // --- layer 1: T1 = h @ Wf + bf (bf16, MFMA);  z1 = gather(T1) + b1 ---
    gemm_l1<<<blkT, 384, 0, stream>>>(h, Wf, bf, T);
    gather_stats<<<NB_GATH, 192, 0, stream>>>(T, rp, cols, b1, z, psums, psq);
    bn_finalize<<<1, 384, 0, stream>>>(psums, psq, g1, be1, scale, shift);

    // --- layer 2: T2 = relu(bn1(z1)) @ W2 (bf16, MFMA);  z2 = gather + b2 ---
    gemm_l2<<<blkT, 384, 0, stream>>>(z, W2, scale, shift, T);
    gather_stats<<<NB_GATH, 192, 0, stream>>>(T, rp, cols, b2, z, psums, psq);
    bn_finalize<<<1, 384, 0, stream>>>(psums, psq, g2, be2, scale, shift);

    // --- readout (BN2+ReLU fused) + log_softmax ---
    readout_kernel<<<2048, 256, 0, stream>>>(z, scale, shift, Wr, br, (float*)d_out);
}

// Round 14
// 310.947 us; speedup vs baseline: 1.2442x; 1.0399x over previous
//
#include <hip/hip_runtime.h>
#include <cmath>

#define N_NODES 100000
#define N_EDGES 1600000
#define IN_DIM 128
#define HID 96
#define NCLS 16
#define NB_GATH 2560  // gather grid (fixed, for stats partials)

// bucket-sort CSR build (contention-free)
#define BSHIFT 7
#define BNODES 128                 // nodes per bucket
#define NBUK 782                   // ceil(N_NODES/128)
#define TILE_E 8192                // edges per tile
#define NBLK_E 196                 // ceil(N_EDGES/TILE_E)
#define NBLK_Q 24                  // NBLK_E/8
#define NBLK_R 4                   // NBLK_E%8

typedef unsigned int uint;
typedef unsigned short ushort;
typedef __attribute__((ext_vector_type(8))) short short8v;   // 8 bf16 (4 VGPRs)
typedef __attribute__((ext_vector_type(4))) float float4v;   // MFMA acc

__device__ __forceinline__ ushort f2bf(float x) {  // RNE f32->bf16
    uint b = __float_as_uint(x);
    uint r = (b + 0x7FFFu + ((b >> 16) & 1u)) >> 16;
    return (ushort)r;
}
__device__ __forceinline__ float bf2f(ushort u) {
    return __uint_as_float(((uint)u) << 16);
}
__device__ __forceinline__ float bf_lo(uint w) { return __uint_as_float(w << 16); }
__device__ __forceinline__ float bf_hi(uint w) { return __uint_as_float(w & 0xFFFF0000u); }
__device__ __forceinline__ uint pack2bf(float a, float b) {
    return (uint)f2bf(a) | ((uint)f2bf(b) << 16);
}

// XCD-swizzled tile mapping (bijective for NBLK_E = 8*NBLK_Q + NBLK_R).
__device__ __forceinline__ int tile_of(int blk) {
    int xcd = blk & 7, slot = blk >> 3;
    return (xcd < NBLK_R) ? xcd * (NBLK_Q + 1) + slot
                          : NBLK_R * (NBLK_Q + 1) + (xcd - NBLK_R) * NBLK_Q + slot;
}

// ---------------------------------------------------------------------------
// wfuse: Wf[128][96] = W_emb @ W1 ; bf[96] = b_emb @ W1
// ---------------------------------------------------------------------------
__global__ __launch_bounds__(256) void wfuse(const float* __restrict__ W_emb,
                                             const float* __restrict__ W1,
                                             const float* __restrict__ b_emb,
                                             float* __restrict__ Wf,
                                             float* __restrict__ bf) {
    __shared__ float W1s[HID * HID];
    for (int i = threadIdx.x; i < HID * HID / 4; i += 256)
        ((float4*)W1s)[i] = ((const float4*)W1)[i];
    __syncthreads();
    int idx = blockIdx.x * 256 + threadIdx.x;
    if (idx < IN_DIM * HID) {
        int i = idx / HID, j = idx - (idx / HID) * HID;
        float acc = 0.f;
        for (int k = 0; k < HID; ++k)
            acc = fmaf(W_emb[(size_t)i * HID + k], W1s[k * HID + j], acc);
        Wf[idx] = acc;
    }
    if (idx < HID) {
        float acc = 0.f;
        for (int k = 0; k < HID; ++k)
            acc = fmaf(b_emb[k], W1s[k * HID + idx], acc);
        bf[idx] = acc;
    }
}

// ---------------------------------------------------------------------------
// MFMA layer-1 GEMM: T1 = bf16(X) @ Wf + bf -> bf16 table. (round 13)
// ---------------------------------------------------------------------------
__global__ __launch_bounds__(384) void gemm_l1(const float* __restrict__ X,
                                               const float* __restrict__ W,
                                               const float* __restrict__ bias,
                                               ushort* __restrict__ outB) {
    constexpr int K = IN_DIM, KPAD = K + 8;
    __shared__ ushort A_s[96 * KPAD];
    __shared__ ushort W_t[96 * KPAD];
    __shared__ float bs[HID];
    if (threadIdx.x < HID) bs[threadIdx.x] = bias[threadIdx.x];

    const int rbase = blockIdx.x * 96;
    for (int c = threadIdx.x; c < 96 * (K / 8); c += 384) {
        int row = c / (K / 8), ko = (c - row * (K / 8)) * 8;
        int gr = min(rbase + row, N_NODES - 1);
        const float* xp = X + (size_t)gr * K + ko;
        float4 v0 = *(const float4*)xp;
        float4 v1 = *(const float4*)(xp + 4);
        uint4 p;
        p.x = pack2bf(v0.x, v0.y);
        p.y = pack2bf(v0.z, v0.w);
        p.z = pack2bf(v1.x, v1.y);
        p.w = pack2bf(v1.z, v1.w);
        *(uint4*)&A_s[row * KPAD + ko] = p;
    }
    for (int j = threadIdx.x; j < K * HID; j += 384) {
        int k = j / HID, n = j - k * HID;
        W_t[n * KPAD + k] = f2bf(W[j]);
    }
    __syncthreads();

    const int lane = threadIdx.x & 63, w = threadIdx.x >> 6;
    const int ar = lane & 15, kg = lane >> 4;
    float4v acc[6] = {};
    const ushort* ap = &A_s[(w * 16 + ar) * KPAD + kg * 8];
    const ushort* bp = &W_t[ar * KPAD + kg * 8];
#pragma unroll
    for (int kc = 0; kc < K / 32; ++kc) {
        short8v af = *(const short8v*)(ap + kc * 32);
#pragma unroll
        for (int ct = 0; ct < 6; ++ct) {
            short8v bfv = *(const short8v*)(bp + ct * 16 * KPAD + kc * 32);
            acc[ct] = __builtin_amdgcn_mfma_f32_16x16x32_bf16(af, bfv, acc[ct], 0, 0, 0);
        }
    }
#pragma unroll
    for (int ct = 0; ct < 6; ++ct) {
        int col = ct * 16 + ar;
        float bb = bs[col];
#pragma unroll
        for (int i = 0; i < 4; ++i) {
            int grow = rbase + w * 16 + kg * 4 + i;
            if (grow < N_NODES)
                outB[(size_t)grow * HID + col] = f2bf(acc[ct][i] + bb);
        }
    }
}

// ---------------------------------------------------------------------------
// MFMA layer-2 GEMM: T2 = relu(bn1(z1)) @ W2 -> bf16. (round 13)
// ---------------------------------------------------------------------------
__global__ __launch_bounds__(384) void gemm_l2(const ushort* __restrict__ X,
                                               const float* __restrict__ W,
                                               const float* __restrict__ scale,
                                               const float* __restrict__ shift,
                                               ushort* __restrict__ outB) {
    constexpr int K = HID, KPAD = K + 8;
    __shared__ ushort A_s[96 * KPAD];
    __shared__ ushort W_t[96 * KPAD];
    __shared__ float scs[HID], shs[HID];
    if (threadIdx.x < HID) {
        scs[threadIdx.x] = scale[threadIdx.x];
        shs[threadIdx.x] = shift[threadIdx.x];
    }
    __syncthreads();

    const int rbase = blockIdx.x * 96;
    for (int c = threadIdx.x; c < 96 * (K / 8); c += 384) {
        int row = c / (K / 8), ko = (c - row * (K / 8)) * 8;
        int gr = min(rbase + row, N_NODES - 1);
        uint4 u = *(const uint4*)(X + (size_t)gr * K + ko);
        float4 sA = *(const float4*)&scs[ko], sB = *(const float4*)&scs[ko + 4];
        float4 hA = *(const float4*)&shs[ko], hB = *(const float4*)&shs[ko + 4];
        float v0 = fmaxf(fmaf(bf_lo(u.x), sA.x, hA.x), 0.f);
        float v1 = fmaxf(fmaf(bf_hi(u.x), sA.y, hA.y), 0.f);
        float v2 = fmaxf(fmaf(bf_lo(u.y), sA.z, hA.z), 0.f);
        float v3 = fmaxf(fmaf(bf_hi(u.y), sA.w, hA.w), 0.f);
        float v4 = fmaxf(fmaf(bf_lo(u.z), sB.x, hB.x), 0.f);
        float v5 = fmaxf(fmaf(bf_hi(u.z), sB.y, hB.y), 0.f);
        float v6 = fmaxf(fmaf(bf_lo(u.w), sB.z, hB.z), 0.f);
        float v7 = fmaxf(fmaf(bf_hi(u.w), sB.w, hB.w), 0.f);
        uint4 p;
        p.x = pack2bf(v0, v1);
        p.y = pack2bf(v2, v3);
        p.z = pack2bf(v4, v5);
        p.w = pack2bf(v6, v7);
        *(uint4*)&A_s[row * KPAD + ko] = p;
    }
    for (int j = threadIdx.x; j < K * HID; j += 384) {
        int k = j / HID, n = j - k * HID;
        W_t[n * KPAD + k] = f2bf(W[j]);
    }
    __syncthreads();

    const int lane = threadIdx.x & 63, w = threadIdx.x >> 6;
    const int ar = lane & 15, kg = lane >> 4;
    float4v acc[6] = {};
    const ushort* ap = &A_s[(w * 16 + ar) * KPAD + kg * 8];
    const ushort* bp = &W_t[ar * KPAD + kg * 8];
#pragma unroll
    for (int kc = 0; kc < K / 32; ++kc) {
        short8v af = *(const short8v*)(ap + kc * 32);
#pragma unroll
        for (int ct = 0; ct < 6; ++ct) {
            short8v bfv = *(const short8v*)(bp + ct * 16 * KPAD + kc * 32);
            acc[ct] = __builtin_amdgcn_mfma_f32_16x16x32_bf16(af, bfv, acc[ct], 0, 0, 0);
        }
    }
#pragma unroll
    for (int ct = 0; ct < 6; ++ct) {
        int col = ct * 16 + ar;
#pragma unroll
        for (int i = 0; i < 4; ++i) {
            int grow = rbase + w * 16 + kg * 4 + i;
            if (grow < N_NODES)
                outB[(size_t)grow * HID + col] = f2bf(acc[ct][i]);
        }
    }
}

// ---------------------------------------------------------------------------
// CSR build, contention-free.
// ---------------------------------------------------------------------------
__global__ __launch_bounds__(256) void bin_hist(const int* __restrict__ dst,
                                                int* __restrict__ bcnt) {
    int tile = tile_of(blockIdx.x);
    int beg = tile * TILE_E, end = min(beg + TILE_E, N_EDGES);
    __shared__ int cnt[NBUK];
    for (int b = threadIdx.x; b < NBUK; b += 256) cnt[b] = 0;
    __syncthreads();
    for (int i = beg + threadIdx.x * 4; i < end; i += 256 * 4) {
        int4 d = *(const int4*)(dst + i);
        atomicAdd(&cnt[d.x >> BSHIFT], 1);
        atomicAdd(&cnt[d.y >> BSHIFT], 1);
        atomicAdd(&cnt[d.z >> BSHIFT], 1);
        atomicAdd(&cnt[d.w >> BSHIFT], 1);
    }
    __syncthreads();
    for (int b = threadIdx.x; b < NBUK; b += 256) bcnt[(size_t)b * NBLK_E + tile] = cnt[b];
}

__global__ __launch_bounds__(256) void bin_scanA(const int* __restrict__ bcnt,
                                                 int* __restrict__ boff,
                                                 int* __restrict__ btot) {
    int bin = blockIdx.x, t = threadIdx.x;
    __shared__ int tmp[256];
    int v = (t < NBLK_E) ? bcnt[(size_t)bin * NBLK_E + t] : 0;
    tmp[t] = v;
    __syncthreads();
    for (int off = 1; off < 256; off <<= 1) {
        int a = (t >= off) ? tmp[t - off] : 0;
        __syncthreads();
        tmp[t] += a;
        __syncthreads();
    }
    if (t < NBLK_E) boff[(size_t)bin * NBLK_E + t] = tmp[t] - v;
    if (t == NBLK_E - 1) btot[bin] = tmp[t];
}

// 782-entry exclusive scan; out[NBUK] = N_EDGES
__global__ __launch_bounds__(1024) void exscan782(const int* __restrict__ in,
                                                  int* __restrict__ out) {
    int t = threadIdx.x;
    __shared__ int tmp[1024];
    int v = (t < NBUK) ? in[t] : 0;
    tmp[t] = v;
    __syncthreads();
    for (int off = 1; off < 1024; off <<= 1) {
        int a = (t >= off) ? tmp[t - off] : 0;
        __syncthreads();
        tmp[t] += a;
        __syncthreads();
    }
    if (t < NBUK) out[t] = tmp[t] - v;
    if (t == 0) out[NBUK] = N_EDGES;
}

__global__ __launch_bounds__(256) void bin_scatter(const int* __restrict__ src,
                                                   const int* __restrict__ dst,
                                                   const int* __restrict__ bbase,
                                                   const int* __restrict__ boff,
                                                   int* __restrict__ ebuf) {
    int tile = tile_of(blockIdx.x);
    int beg = tile * TILE_E, end = min(beg + TILE_E, N_EDGES);
    __shared__ int curs[NBUK];
    for (int b = threadIdx.x; b < NBUK; b += 256)
        curs[b] = bbase[b] + boff[(size_t)b * NBLK_E + tile];
    __syncthreads();
    for (int i = beg + threadIdx.x * 4; i < end; i += 256 * 4) {
        int4 d = *(const int4*)(dst + i);
        int4 s = *(const int4*)(src + i);
#pragma unroll
        for (int e = 0; e < 4; ++e) {
            int dv = e == 0 ? d.x : e == 1 ? d.y : e == 2 ? d.z : d.w;
            int sv = e == 0 ? s.x : e == 1 ? s.y : e == 2 ? s.z : s.w;
            int p = atomicAdd(&curs[dv >> BSHIFT], 1);  // LDS atomic: cheap
            ebuf[p] = (sv << BSHIFT) | (dv & (BNODES - 1));
        }
    }
}

// ---------------------------------------------------------------------------
// bucket_finalize: merged bucket_hist + scan_final + bucket_place.
// Key: rp base for bucket b IS bbase[b] (buckets contiguous & node-ordered),
// so the second global exscan is unnecessary. One kernel: LDS degree count
// from the bucket's ebuf run -> LDS 128-scan -> write rp -> place cols.
// ---------------------------------------------------------------------------
__global__ __launch_bounds__(256) void bucket_finalize(const int* __restrict__ ebuf,
                                                       const int* __restrict__ bbase,
                                                       int* __restrict__ rp,
                                                       int* __restrict__ cols) {
    int b = blockIdx.x;
    int lo = b << BSHIFT;
    __shared__ int cnt[BNODES];
    __shared__ int cur[BNODES];
    if (threadIdx.x < BNODES) cnt[threadIdx.x] = 0;
    __syncthreads();
    int beg = bbase[b], end = bbase[b + 1];
    for (int i = beg + threadIdx.x; i < end; i += 256)
        atomicAdd(&cnt[ebuf[i] & (BNODES - 1)], 1);
    __syncthreads();
    int t = threadIdx.x;
    int val = (t < BNODES) ? cnt[t] : 0;
    if (t < BNODES) cur[t] = val;
    __syncthreads();
    for (int off = 1; off < BNODES; off <<= 1) {
        int a = (t < BNODES && t >= off) ? cur[t - off] : 0;
        __syncthreads();
        if (t < BNODES) cur[t] += a;
        __syncthreads();
    }
    if (t < BNODES) {
        int excl = beg + cur[t] - val;  // inclusive -> exclusive + bucket base
        if (lo + t < N_NODES) {
            rp[lo + t] = excl;
            if (lo + t == N_NODES - 1) rp[N_NODES] = N_EDGES;
        }
        cur[t] = excl;  // reuse as placement cursor
    }
    __syncthreads();
    for (int i = beg + threadIdx.x; i < end; i += 256) {
        int v = ebuf[i];
        int p = atomicAdd(&cur[v & (BNODES - 1)], 1);
        cols[p] = v >> BSHIFT;
    }
}

// ---------------------------------------------------------------------------
// Gather + fused BN stats, 24 lanes/node x 8 B; 8-wide neighbor unroll
// (mean degree 16 -> 2 iters, more loads in flight; kernel is L2-fill
// latency bound: Occ 55%, VALU 21%).
// ---------------------------------------------------------------------------
#define GLANES 24
#define GNODES 8  // 192 threads / 24 lanes

__global__ __launch_bounds__(192) void gather_stats(const ushort* __restrict__ T,
                                                    const int* __restrict__ rp,
                                                    const int* __restrict__ cols,
                                                    const float* __restrict__ bias,
                                                    ushort* __restrict__ z,
                                                    float* __restrict__ psums,
                                                    float* __restrict__ psq) {
    const int q = threadIdx.x % GLANES;   // 4-column chunk
    const int rs = threadIdx.x / GLANES;  // node slot 0..7
    const float4 bias4 = ((const float4*)bias)[q];
    float4 s = make_float4(0.f, 0.f, 0.f, 0.f);
    float4 sq = make_float4(0.f, 0.f, 0.f, 0.f);

#define ADDROW(u)                                                              \
    {                                                                          \
        ushort4 w = *(const ushort4*)(T + (size_t)(u) * HID + q * 4);          \
        a.x += bf2f(w.x); a.y += bf2f(w.y);                                    \
        a.z += bf2f(w.z); a.w += bf2f(w.w);                                    \
    }

    for (int v = blockIdx.x * GNODES + rs; v < N_NODES; v += NB_GATH * GNODES) {
        float4 a = bias4;
        ADDROW(v);
        int beg = rp[v], end = rp[v + 1];
        int j = beg;
        for (; j + 7 < end; j += 8) {
            int u0 = cols[j], u1 = cols[j + 1], u2 = cols[j + 2], u3 = cols[j + 3];
            int u4 = cols[j + 4], u5 = cols[j + 5], u6 = cols[j + 6], u7 = cols[j + 7];
            ADDROW(u0); ADDROW(u1); ADDROW(u2); ADDROW(u3);
            ADDROW(u4); ADDROW(u5); ADDROW(u6); ADDROW(u7);
        }
        for (; j + 3 < end; j += 4) {
            int u0 = cols[j], u1 = cols[j + 1], u2 = cols[j + 2], u3 = cols[j + 3];
            ADDROW(u0); ADDROW(u1); ADDROW(u2); ADDROW(u3);
        }
        for (; j < end; ++j) ADDROW(cols[j]);

        uint2 o;
        o.x = pack2bf(a.x, a.y);
        o.y = pack2bf(a.z, a.w);
        *(uint2*)(z + (size_t)v * HID + q * 4) = o;
        s.x += a.x; s.y += a.y; s.z += a.z; s.w += a.w;
        sq.x = fmaf(a.x, a.x, sq.x);
        sq.y = fmaf(a.y, a.y, sq.y);
        sq.z = fmaf(a.z, a.z, sq.z);
        sq.w = fmaf(a.w, a.w, sq.w);
    }
#undef ADDROW

    __shared__ float4 ls[GNODES][GLANES], lq[GNODES][GLANES];
    ls[rs][q] = s;
    lq[rs][q] = sq;
    __syncthreads();
    if (threadIdx.x < GLANES) {
        float4 S = ls[0][threadIdx.x], Q = lq[0][threadIdx.x];
#pragma unroll
        for (int i = 1; i < GNODES; ++i) {
            S.x += ls[i][threadIdx.x].x; S.y += ls[i][threadIdx.x].y;
            S.z += ls[i][threadIdx.x].z; S.w += ls[i][threadIdx.x].w;
            Q.x += lq[i][threadIdx.x].x; Q.y += lq[i][threadIdx.x].y;
            Q.z += lq[i][threadIdx.x].z; Q.w += lq[i][threadIdx.x].w;
        }
        ((float4*)(psums + (size_t)blockIdx.x * HID))[threadIdx.x] = S;
        ((float4*)(psq + (size_t)blockIdx.x * HID))[threadIdx.x] = Q;
    }
}

// ---------------------------------------------------------------------------
__global__ __launch_bounds__(384) void bn_finalize(const float* __restrict__ psums,
                                                   const float* __restrict__ psq,
                                                   const float* __restrict__ g,
                                                   const float* __restrict__ be,
                                                   float* __restrict__ scale,
                                                   float* __restrict__ shift) {
    int c = threadIdx.x % 96, h = threadIdx.x / 96;
    float S = 0.f, Q = 0.f;
    for (int b = h * (NB_GATH / 4); b < (h + 1) * (NB_GATH / 4); ++b) {
        S += psums[(size_t)b * HID + c];
        Q += psq[(size_t)b * HID + c];
    }
    __shared__ float lS[4][96], lQ[4][96];
    lS[h][c] = S;
    lQ[h][c] = Q;
    __syncthreads();
    if (threadIdx.x < 96) {
        S = lS[0][c] + lS[1][c] + lS[2][c] + lS[3][c];
        Q = lQ[0][c] + lQ[1][c] + lQ[2][c] + lQ[3][c];
        float mu = S * (1.0f / N_NODES);
        float var = Q * (1.0f / N_NODES) - mu * mu;
        float rstd = rsqrtf(var + 1e-5f);
        float sc = g[c] * rstd;
        scale[c] = sc;
        shift[c] = be[c] - mu * sc;
    }
}

// ---------------------------------------------------------------------------
// Readout: bf16 input, BN2+ReLU fused during LDS staging, 16 lanes/row
// shuffle log_softmax, coalesced store.
// ---------------------------------------------------------------------------
__global__ __launch_bounds__(256) void readout_kernel(const ushort* __restrict__ X,
                                                      const float* __restrict__ scale,
                                                      const float* __restrict__ shift,
                                                      const float* __restrict__ Wr,
                                                      const float* __restrict__ br,
                                                      float* __restrict__ out) {
    __shared__ float Ws[HID * NCLS];
    __shared__ float XL[16 * 97];
    __shared__ float scs[HID], shs[HID], bs[NCLS];
    for (int i = threadIdx.x; i < HID * NCLS / 4; i += 256)
        ((float4*)Ws)[i] = ((const float4*)Wr)[i];
    if (threadIdx.x < HID) {
        scs[threadIdx.x] = scale[threadIdx.x];
        shs[threadIdx.x] = shift[threadIdx.x];
    }
    if (threadIdx.x < NCLS) bs[threadIdx.x] = br[threadIdx.x];

    int rr = threadIdx.x >> 4, t = threadIdx.x & 15;
    for (int tile = blockIdx.x; tile < N_NODES / 16; tile += gridDim.x) {
        int rbase = tile * 16;
        __syncthreads();
        if (threadIdx.x < 192) {  // 16 rows x 96 cols / 8 per thread
            int base = threadIdx.x * 8;
            int row = base / HID, col = base - (base / HID) * HID;
            uint4 w = *(const uint4*)(X + (size_t)rbase * HID + base);
            float v[8] = {bf_lo(w.x), bf_hi(w.x), bf_lo(w.y), bf_hi(w.y),
                          bf_lo(w.z), bf_hi(w.z), bf_lo(w.w), bf_hi(w.w)};
#pragma unroll
            for (int e = 0; e < 8; ++e)
                XL[row * 97 + col + e] = fmaxf(fmaf(v[e], scs[col + e], shs[col + e]), 0.f);
        }
        __syncthreads();
        float acc = bs[t];
        const float* xrow = &XL[rr * 97];
#pragma unroll 4
        for (int k = 0; k < HID; ++k) acc = fmaf(xrow[k], Ws[k * NCLS + t], acc);
        float m = acc;
#pragma unroll
        for (int off = 8; off; off >>= 1) m = fmaxf(m, __shfl_xor(m, off, 16));
        float e = expf(acc - m);
        float sum = e;
#pragma unroll
        for (int off = 8; off; off >>= 1) sum += __shfl_xor(sum, off, 16);
        float lse = m + logf(sum);
        out[(size_t)rbase * NCLS + threadIdx.x] = acc - lse;
    }
}

// ---------------------------------------------------------------------------
extern "C" void kernel_launch(void* const* d_in, const int* in_sizes, int n_in,
                              void* d_out, int out_size, void* d_ws, size_t ws_size,
                              hipStream_t stream) {
    const float* h     = (const float*)d_in[0];
    const int*   src   = (const int*)d_in[1];
    const int*   dst   = (const int*)d_in[2];
    const float* W_emb = (const float*)d_in[3];
    const float* b_emb = (const float*)d_in[4];
    const float* W1    = (const float*)d_in[5];
    const float* b1    = (const float*)d_in[6];
    const float* g1    = (const float*)d_in[7];
    const float* be1   = (const float*)d_in[8];
    const float* W2    = (const float*)d_in[9];
    const float* b2    = (const float*)d_in[10];
    const float* g2    = (const float*)d_in[11];
    const float* be2   = (const float*)d_in[12];
    const float* Wr    = (const float*)d_in[13];
    const float* br    = (const float*)d_in[14];

    const size_t nh = (size_t)N_NODES * HID;
    ushort* z    = (ushort*)d_ws;             // 19.2 MB bf16 (z1, then z2)
    ushort* T    = z + nh;                    // 19.2 MB bf16 table
    int* rp      = (int*)(T + nh);            // N+1
    int* cols    = rp + N_NODES + 1;          // E (6.4 MB)
    int* ebuf    = cols + N_EDGES;            // E (6.4 MB, bucket-sorted packed)
    int* bcnt    = ebuf + N_EDGES;            // NBUK*NBLK_E
    int* boff    = bcnt + NBUK * NBLK_E;      // NBUK*NBLK_E
    int* btot    = boff + NBUK * NBLK_E;      // NBUK
    int* bbase   = btot + NBUK;               // NBUK+1
    float* psums = (float*)(bbase + NBUK + 1);  // NB_GATH*96
    float* psq   = psums + (size_t)NB_GATH * HID;
    float* scale = psq + (size_t)NB_GATH * HID;   // 96
    float* shift = scale + HID;                    // 96
    float* Wf    = shift + HID;                    // 128*96
    float* bf    = Wf + IN_DIM * HID;              // 96

    const int blkT = (N_NODES + 95) / 96;     // 1042

    // --- CSR build: tile-hist -> scans -> deterministic scatter -> finalize ---
    bin_hist<<<NBLK_E, 256, 0, stream>>>(dst, bcnt);
    bin_scanA<<<NBUK, 256, 0, stream>>>(bcnt, boff, btot);
    exscan782<<<1, 1024, 0, stream>>>(btot, bbase);
    bin_scatter<<<NBLK_E, 256, 0, stream>>>(src, dst, bbase, boff, ebuf);
    bucket_finalize<<<NBUK, 256, 0, stream>>>(ebuf, bbase, rp, cols);
    wfuse<<<(IN_DIM * HID + 255) / 256, 256, 0, stream>>>(W_emb, W1, b_emb, Wf, bf);

    // --- layer 1: T1 = h @ Wf + bf (bf16, MFMA);  z1 = gather(T1) + b1 ---
    gemm_l1<<<blkT, 384, 0, stream>>>(h, Wf, bf, T);
    gather_stats<<<NB_GATH, 192, 0, stream>>>(T, rp, cols, b1, z, psums, psq);
    bn_finalize<<<1, 384, 0, stream>>>(psums, psq, g1, be1, scale, shift);

    // --- layer 2: T2 = relu(bn1(z1)) @ W2 (bf16, MFMA);  z2 = gather + b2 ---
    gemm_l2<<<blkT, 384, 0, stream>>>(z, W2, scale, shift, T);
    gather_stats<<<NB_GATH, 192, 0, stream>>>(T, rp, cols, b2, z, psums, psq);
    bn_finalize<<<1, 384, 0, stream>>>(psums, psq, g2, be2, scale, shift);

    // --- readout (BN2+ReLU fused) + log_softmax ---
    readout_kernel<<<2048, 256, 0, stream>>>(z, scale, shift, Wr, br, (float*)d_out);
}